// Round 14
// baseline (594.118 us; speedup 1.0000x reference)
//
#include <hip/hip_runtime.h>
#include <math.h>

#define NN 100000
#define NE 1600000
#define NG 64

typedef unsigned short u16;
typedef unsigned int u32;
typedef __attribute__((ext_vector_type(8))) short short8;   // 8 bf16 = 4 VGPR
typedef __attribute__((ext_vector_type(4))) float f32x4;    // MFMA C/D

__device__ __forceinline__ float gelu_f(float x) {
    return 0.5f * x * (1.0f + erff(x * 0.7071067811865475f));
}
// round-to-nearest-even fp32 -> bf16
__device__ __forceinline__ u16 f2bf(float f) {
    u32 u = __float_as_uint(f);
    u32 r = u + 0x7FFFu + ((u >> 16) & 1u);
    return (u16)(r >> 16);
}
__device__ __forceinline__ float bf2f(u16 h) { return __uint_as_float(((u32)h) << 16); }
// packed hi/lo bf16 pair in one u32: value ~= hi + lo, rel err ~2^-18
__device__ __forceinline__ u32 packf(float v) {
    u16 h = f2bf(v);
    u16 l = f2bf(v - bf2f(h));
    return (((u32)h) << 16) | (u32)l;
}
__device__ __forceinline__ float unpackf(u32 p) {
    return __uint_as_float(p & 0xFFFF0000u) + __uint_as_float(p << 16);
}
// 8 packed elems (2 uint4) -> hi/lo short8 for MFMA A-operand
__device__ __forceinline__ void unpack8(uint4 q0, uint4 q1, short8& hi, short8& lo) {
    u32 v[8] = {q0.x, q0.y, q0.z, q0.w, q1.x, q1.y, q1.z, q1.w};
#pragma unroll
    for (int e = 0; e < 8; ++e) {
        hi[e] = (short)(v[e] >> 16);
        lo[e] = (short)(v[e] & 0xFFFFu);
    }
}
// 8 fp32 elems (2 float4) -> hi/lo short8
__device__ __forceinline__ void cvt8f(float4 f0, float4 f1, short8& hi, short8& lo) {
    float v[8] = {f0.x, f0.y, f0.z, f0.w, f1.x, f1.y, f1.z, f1.w};
#pragma unroll
    for (int e = 0; e < 8; ++e) {
        u16 h = f2bf(v[e]);
        hi[e] = (short)h;
        lo[e] = (short)f2bf(v[e] - bf2f(h));
    }
}
#define MFMA __builtin_amdgcn_mfma_f32_16x16x32_bf16

// ---------------- CSR build ----------------
__global__ void k_hist(const int* __restrict__ dstp, int* __restrict__ cnt) {
    int e = blockIdx.x * 256 + threadIdx.x;
    if (e < NE) atomicAdd(&cnt[dstp[e]], 1);
}

#define SB 1024
__global__ __launch_bounds__(SB) void k_scan1(const int* __restrict__ cnt, int* __restrict__ rowp,
                                              int* __restrict__ blksum) {
    __shared__ int s[SB];
    int tid = threadIdx.x;
    int i = blockIdx.x * SB + tid;
    int v = (i < NN) ? cnt[i] : 0;
    int run = v;
    s[tid] = v;
    __syncthreads();
    for (int off = 1; off < SB; off <<= 1) {
        int t = (tid >= off) ? s[tid - off] : 0;
        __syncthreads();
        run += t;
        s[tid] = run;
        __syncthreads();
    }
    if (i < NN) rowp[i] = run - v;
    if (tid == SB - 1) blksum[blockIdx.x] = run;
}

__global__ void k_scan2(const int* __restrict__ blksum, int* __restrict__ blkoff, int nb) {
    __shared__ int s[128];
    int tid = threadIdx.x;
    int v = (tid < nb) ? blksum[tid] : 0;
    int run = v;
    s[tid] = v;
    __syncthreads();
    for (int off = 1; off < 128; off <<= 1) {
        int t = (tid >= off) ? s[tid - off] : 0;
        __syncthreads();
        run += t;
        s[tid] = run;
        __syncthreads();
    }
    if (tid < nb) blkoff[tid] = run - v;
}

// writes rowp AND the scatter cursor copy rowp2 (replaces fill[] + its memset)
__global__ void k_scan3(int* __restrict__ rowp, const int* __restrict__ blkoff,
                        int* __restrict__ rowp2) {
    int i = blockIdx.x * 256 + threadIdx.x;
    if (i < NN) {
        int v = rowp[i] + blkoff[i >> 10];
        rowp[i] = v;
        rowp2[i] = v;
    } else if (i == NN) {
        rowp[NN] = NE;
    }
}

__global__ void k_scatter(const int* __restrict__ srcp, const int* __restrict__ dstp,
                          int* __restrict__ rowp2, int* __restrict__ cidx) {
    int e = blockIdx.x * 256 + threadIdx.x;
    if (e < NE) {
        int pos = atomicAdd(&rowp2[dstp[e]], 1);   // old value IS the slot
        cidx[pos] = srcp[e];
    }
}

// ---------------- mean-aggregate: 32 lanes x 16B per node, 8 edges in flight ----------------
// PACKED=0: src rows are fp32 (x). PACKED=1: src rows hi/lo-packed u32.
// Output packed u32 (GEMM-A-ready). r8-proven config: ~117us, fabric-bound 3.7TB/s
// (pattern ceiling confirmed by r8/r11/r12 variants; byte cuts fail precision).
template <int PACKED>
__global__ __launch_bounds__(256) void k_agg(const void* __restrict__ xin, const int* __restrict__ rowp,
                                             const int* __restrict__ cidx, u32* __restrict__ agg) {
    int tid = blockIdx.x * 256 + threadIdx.x;
    int node = tid >> 5;
    int lane = tid & 31;
    if (node >= NN) return;
    int beg = rowp[node], endp = rowp[node + 1];
    const float4* xf = (const float4*)xin;
    const uint4* xp = (const uint4*)xin;
    float sx = 0.f, sy = 0.f, sz = 0.f, sw = 0.f;
    int e = beg;
    for (; e + 7 < endp; e += 8) {
        int idx[8];
#pragma unroll
        for (int u = 0; u < 8; ++u) idx[u] = cidx[e + u];
        if (PACKED) {
            uint4 q[8];
#pragma unroll
            for (int u = 0; u < 8; ++u) q[u] = xp[(size_t)idx[u] * 32 + lane];
#pragma unroll
            for (int u = 0; u < 8; ++u) {
                sx += unpackf(q[u].x); sy += unpackf(q[u].y);
                sz += unpackf(q[u].z); sw += unpackf(q[u].w);
            }
        } else {
            float4 v[8];
#pragma unroll
            for (int u = 0; u < 8; ++u) v[u] = xf[(size_t)idx[u] * 32 + lane];
#pragma unroll
            for (int u = 0; u < 8; ++u) {
                sx += v[u].x; sy += v[u].y; sz += v[u].z; sw += v[u].w;
            }
        }
    }
    for (; e < endp; ++e) {
        int i0 = cidx[e];
        if (PACKED) {
            uint4 q = xp[(size_t)i0 * 32 + lane];
            sx += unpackf(q.x); sy += unpackf(q.y); sz += unpackf(q.z); sw += unpackf(q.w);
        } else {
            float4 v = xf[(size_t)i0 * 32 + lane];
            sx += v.x; sy += v.y; sz += v.z; sw += v.w;
        }
    }
    float inv = 1.0f / fmaxf((float)(endp - beg), 1.0f);
    uint4 o;
    o.x = packf(sx * inv); o.y = packf(sy * inv); o.z = packf(sz * inv); o.w = packf(sw * inv);
    ((uint4*)agg)[(size_t)node * 32 + lane] = o;
}

// ---------------- weight prep: transpose + bf16 hi/lo split (planes) ----------------
__global__ __launch_bounds__(256) void k_cvtw(const float* __restrict__ W0, const float* __restrict__ W1,
                                              const float* __restrict__ W2, const float* __restrict__ W3,
                                              const float* __restrict__ W4, u16* __restrict__ dst) {
    int idx = blockIdx.x * 256 + threadIdx.x;   // 5*16384
    int m = idx >> 14;
    int r = idx & 16383;
    int k = r >> 7, c = r & 127;
    const float* W = (m == 0) ? W0 : (m == 1) ? W1 : (m == 2) ? W2 : (m == 3) ? W3 : W4;
    float v = W[k * 128 + c];
    u16 h = f2bf(v);
    u16 l = f2bf(v - bf2f(h));
    u16* base = dst + (size_t)m * 32768;
    base[c * 128 + k] = h;
    base[16384 + c * 128 + k] = l;
}

// ---------------- fused SAGE layer via bf16x3 MFMA, A-prefetch pipelined ----------------
// 512 thr = 8 waves; wave = 32 nodes (2 M-tiles); block = 256 nodes.
// In-place safety (out may alias A1/A2): wave reads/writes ONLY its own 32 rows;
// prefetch loads are consumed before epilogue stores (wave program order).
template <int A2F32>
__global__ __launch_bounds__(512, 2) void k_sage_mf(const u32* A1, const u16* __restrict__ w1hi,
                                                    const u16* __restrict__ w1lo, const float* __restrict__ b1,
                                                    const void* A2v, const u16* __restrict__ w2hi,
                                                    const u16* __restrict__ w2lo, u32* out) {
    __shared__ u16 lds[4][128][40];
    const int t = threadIdx.x;
    const int lane = t & 63;
    const int w = t >> 6;
    const int l15 = lane & 15;
    const int lg = lane >> 4;
    const int n0 = blockIdx.x * 256 + w * 32;
    f32x4 acc[2][8];
#pragma unroll
    for (int ti = 0; ti < 2; ++ti)
#pragma unroll
        for (int ct = 0; ct < 8; ++ct) acc[ti][ct] = (f32x4){0.f, 0.f, 0.f, 0.f};
    int nA = n0 + l15;
    int nB = n0 + 16 + l15;
    if (nA >= NN) nA = NN - 1;
    if (nB >= NN) nB = NN - 1;
    const u32* a1A = A1 + (size_t)nA * 128;
    const u32* a1B = A1 + (size_t)nB * 128;
    const u32* a2Ap = (const u32*)A2v + (size_t)nA * 128;
    const u32* a2Bp = (const u32*)A2v + (size_t)nB * 128;
    const float* a2Af = (const float*)A2v + (size_t)nA * 128;
    const float* a2Bf = (const float*)A2v + (size_t)nB * 128;
    const int koff = 8 * lg;

    uint4 p1A[2][2], p1B[2][2];
    uint4 p2A[2][2], p2B[2][2];
    float4 f2A[2][2], f2B[2][2];

    {
        const uint4* q;
        q = (const uint4*)(a1A + koff); p1A[0][0] = q[0]; p1A[0][1] = q[1];
        q = (const uint4*)(a1B + koff); p1B[0][0] = q[0]; p1B[0][1] = q[1];
        if (A2F32) {
            const float4* f;
            f = (const float4*)(a2Af + koff); f2A[0][0] = f[0]; f2A[0][1] = f[1];
            f = (const float4*)(a2Bf + koff); f2B[0][0] = f[0]; f2B[0][1] = f[1];
        } else {
            const uint4* q2;
            q2 = (const uint4*)(a2Ap + koff); p2A[0][0] = q2[0]; p2A[0][1] = q2[1];
            q2 = (const uint4*)(a2Bp + koff); p2B[0][0] = q2[0]; p2B[0][1] = q2[1];
        }
    }
#pragma unroll
    for (int kb = 0; kb < 4; ++kb) {
        const int k0 = kb * 32;
        const int cur = kb & 1, nxt = cur ^ 1;
        __syncthreads();
        {   // stage 4 W-slices [128c][32k] bf16: 512 units of 64B, one per thread
            int s = t >> 7, c = t & 127;
            const u16* src = (s == 0) ? w1hi : (s == 1) ? w1lo : (s == 2) ? w2hi : w2lo;
            const uint4* s4 = (const uint4*)(src + (size_t)c * 128 + k0);
            uint4* d4 = (uint4*)&lds[s][c][0];
            d4[0] = s4[0]; d4[1] = s4[1]; d4[2] = s4[2]; d4[3] = s4[3];
        }
        __syncthreads();
        if (kb < 3) {
            const int kn = k0 + 32 + koff;
            const uint4* q;
            q = (const uint4*)(a1A + kn); p1A[nxt][0] = q[0]; p1A[nxt][1] = q[1];
            q = (const uint4*)(a1B + kn); p1B[nxt][0] = q[0]; p1B[nxt][1] = q[1];
            if (A2F32) {
                const float4* f;
                f = (const float4*)(a2Af + kn); f2A[nxt][0] = f[0]; f2A[nxt][1] = f[1];
                f = (const float4*)(a2Bf + kn); f2B[nxt][0] = f[0]; f2B[nxt][1] = f[1];
            } else {
                const uint4* q2;
                q2 = (const uint4*)(a2Ap + kn); p2A[nxt][0] = q2[0]; p2A[nxt][1] = q2[1];
                q2 = (const uint4*)(a2Bp + kn); p2B[nxt][0] = q2[0]; p2B[nxt][1] = q2[1];
            }
        }
        short8 h1A, l1A, h1B, l1B, h2A, l2A, h2B, l2B;
        unpack8(p1A[cur][0], p1A[cur][1], h1A, l1A);
        unpack8(p1B[cur][0], p1B[cur][1], h1B, l1B);
        if (A2F32) {
            cvt8f(f2A[cur][0], f2A[cur][1], h2A, l2A);
            cvt8f(f2B[cur][0], f2B[cur][1], h2B, l2B);
        } else {
            unpack8(p2A[cur][0], p2A[cur][1], h2A, l2A);
            unpack8(p2B[cur][0], p2B[cur][1], h2B, l2B);
        }
#pragma unroll
        for (int ct = 0; ct < 8; ++ct) {
            int c = ct * 16 + l15;
            short8 bh1 = *(const short8*)&lds[0][c][koff];
            short8 bl1 = *(const short8*)&lds[1][c][koff];
            short8 bh2 = *(const short8*)&lds[2][c][koff];
            short8 bl2 = *(const short8*)&lds[3][c][koff];
            acc[0][ct] = MFMA(h1A, bh1, acc[0][ct], 0, 0, 0);
            acc[0][ct] = MFMA(l1A, bh1, acc[0][ct], 0, 0, 0);
            acc[0][ct] = MFMA(h1A, bl1, acc[0][ct], 0, 0, 0);
            acc[0][ct] = MFMA(h2A, bh2, acc[0][ct], 0, 0, 0);
            acc[0][ct] = MFMA(l2A, bh2, acc[0][ct], 0, 0, 0);
            acc[0][ct] = MFMA(h2A, bl2, acc[0][ct], 0, 0, 0);
            acc[1][ct] = MFMA(h1B, bh1, acc[1][ct], 0, 0, 0);
            acc[1][ct] = MFMA(l1B, bh1, acc[1][ct], 0, 0, 0);
            acc[1][ct] = MFMA(h1B, bl1, acc[1][ct], 0, 0, 0);
            acc[1][ct] = MFMA(h2B, bh2, acc[1][ct], 0, 0, 0);
            acc[1][ct] = MFMA(l2B, bh2, acc[1][ct], 0, 0, 0);
            acc[1][ct] = MFMA(h2B, bl2, acc[1][ct], 0, 0, 0);
        }
    }
#pragma unroll
    for (int ti = 0; ti < 2; ++ti) {
#pragma unroll
        for (int ct = 0; ct < 8; ++ct) {
            int c = ct * 16 + l15;
            float bb = b1[c];
#pragma unroll
            for (int r = 0; r < 4; ++r) {
                int node = n0 + ti * 16 + lg * 4 + r;
                if (node < NN) out[(size_t)node * 128 + c] = packf(gelu_f(acc[ti][ct][r] + bb));
            }
        }
    }
}

// ---------------- fused gate via bf16x3 MFMA (packed H input) ----------------
__global__ __launch_bounds__(512, 2) void k_gatef_mf(const u32* __restrict__ H, const u16* __restrict__ wghi,
                                                     const u16* __restrict__ wglo, const float* __restrict__ bg1,
                                                     const float* __restrict__ Wg2, float* __restrict__ gate) {
    __shared__ u16 lds[2][128][40];
    const int t = threadIdx.x;
    const int lane = t & 63;
    const int w = t >> 6;
    const int l15 = lane & 15;
    const int lg = lane >> 4;
    const int n0 = blockIdx.x * 256 + w * 32;
    f32x4 acc[2][8];
#pragma unroll
    for (int ti = 0; ti < 2; ++ti)
#pragma unroll
        for (int ct = 0; ct < 8; ++ct) acc[ti][ct] = (f32x4){0.f, 0.f, 0.f, 0.f};
    int nA = n0 + l15;
    int nB = n0 + 16 + l15;
    if (nA >= NN) nA = NN - 1;
    if (nB >= NN) nB = NN - 1;
    const u32* hA = H + (size_t)nA * 128;
    const u32* hB = H + (size_t)nB * 128;
    const int koff = 8 * lg;
    uint4 pA[2][2], pB[2][2];
    {
        const uint4* q;
        q = (const uint4*)(hA + koff); pA[0][0] = q[0]; pA[0][1] = q[1];
        q = (const uint4*)(hB + koff); pB[0][0] = q[0]; pB[0][1] = q[1];
    }
#pragma unroll
    for (int kb = 0; kb < 4; ++kb) {
        const int k0 = kb * 32;
        const int cur = kb & 1, nxt = cur ^ 1;
        __syncthreads();
        if (t < 256) {  // 2 planes x 128 c
            int s = t >> 7, c = t & 127;
            const u16* src = (s == 0) ? wghi : wglo;
            const uint4* s4 = (const uint4*)(src + (size_t)c * 128 + k0);
            uint4* d4 = (uint4*)&lds[s][c][0];
            d4[0] = s4[0]; d4[1] = s4[1]; d4[2] = s4[2]; d4[3] = s4[3];
        }
        __syncthreads();
        if (kb < 3) {
            const int kn = k0 + 32 + koff;
            const uint4* q;
            q = (const uint4*)(hA + kn); pA[nxt][0] = q[0]; pA[nxt][1] = q[1];
            q = (const uint4*)(hB + kn); pB[nxt][0] = q[0]; pB[nxt][1] = q[1];
        }
        short8 hAh, hAl, hBh, hBl;
        unpack8(pA[cur][0], pA[cur][1], hAh, hAl);
        unpack8(pB[cur][0], pB[cur][1], hBh, hBl);
#pragma unroll
        for (int ct = 0; ct < 8; ++ct) {
            int c = ct * 16 + l15;
            short8 bh = *(const short8*)&lds[0][c][koff];
            short8 bl = *(const short8*)&lds[1][c][koff];
            acc[0][ct] = MFMA(hAh, bh, acc[0][ct], 0, 0, 0);
            acc[0][ct] = MFMA(hAl, bh, acc[0][ct], 0, 0, 0);
            acc[0][ct] = MFMA(hAh, bl, acc[0][ct], 0, 0, 0);
            acc[1][ct] = MFMA(hBh, bh, acc[1][ct], 0, 0, 0);
            acc[1][ct] = MFMA(hBl, bh, acc[1][ct], 0, 0, 0);
            acc[1][ct] = MFMA(hBh, bl, acc[1][ct], 0, 0, 0);
        }
    }
    float p[2][4];
#pragma unroll
    for (int ti = 0; ti < 2; ++ti)
#pragma unroll
        for (int r = 0; r < 4; ++r) p[ti][r] = 0.f;
#pragma unroll
    for (int ct = 0; ct < 8; ++ct) {
        int c = ct * 16 + l15;
        float bb = bg1[c];
        float gv = Wg2[c];
#pragma unroll
        for (int ti = 0; ti < 2; ++ti)
#pragma unroll
            for (int r = 0; r < 4; ++r) p[ti][r] += gelu_f(acc[ti][ct][r] + bb) * gv;
    }
#pragma unroll
    for (int m = 1; m < 16; m <<= 1) {
#pragma unroll
        for (int ti = 0; ti < 2; ++ti)
#pragma unroll
            for (int r = 0; r < 4; ++r) p[ti][r] += __shfl_xor(p[ti][r], m);
    }
    if (l15 == 0) {
#pragma unroll
        for (int ti = 0; ti < 2; ++ti)
#pragma unroll
            for (int r = 0; r < 4; ++r) {
                int node = n0 + ti * 16 + lg * 4 + r;
                if (node < NN) gate[node] = p[ti][r];
            }
    }
}

// ---------------- pooling stage 1 (512 thr) ----------------
__global__ __launch_bounds__(512) void k_pstats(const float* __restrict__ gate, const int* __restrict__ batch,
                                                float* __restrict__ gm, float* __restrict__ gden) {
    int g = blockIdx.x;
    int lo = 0, hi = NN;
    while (lo < hi) { int mid = (lo + hi) >> 1; if (batch[mid] < g) lo = mid + 1; else hi = mid; }
    int start = lo;
    lo = start; hi = NN;
    while (lo < hi) { int mid = (lo + hi) >> 1; if (batch[mid] < g + 1) lo = mid + 1; else hi = mid; }
    int endp = lo;

    __shared__ float red[512];
    int tid = threadIdx.x;

    float m = -1e30f;
    for (int i = start + tid; i < endp; i += 512) m = fmaxf(m, gate[i]);
    red[tid] = m;
    __syncthreads();
    for (int off = 256; off; off >>= 1) {
        if (tid < off) red[tid] = fmaxf(red[tid], red[tid + off]);
        __syncthreads();
    }
    m = red[0];
    __syncthreads();

    float s = 0.f;
    for (int i = start + tid; i < endp; i += 512) s += expf(gate[i] - m);
    red[tid] = s;
    __syncthreads();
    for (int off = 256; off; off >>= 1) {
        if (tid < off) red[tid] += red[tid + off];
        __syncthreads();
    }
    if (tid == 0) { gm[g] = m; gden[g] = red[0]; }
}

// ---------------- pooling stage 2 (packed H; 512 thr, 4 rows in flight) ----------------
__global__ __launch_bounds__(512) void k_pacc(const u32* __restrict__ H, const float* __restrict__ gate,
                                              const int* __restrict__ batch, const float* __restrict__ gm,
                                              const float* __restrict__ gden, float* __restrict__ gacc) {
    int c = threadIdx.x & 127;
    int h = threadIdx.x >> 7;          // 0..3
    int n0 = blockIdx.x * 128;
    int nend = n0 + 128;
    if (nend > NN) nend = NN;
    int i = n0 + h;
    if (i >= nend) return;
    int cur = batch[i];
    float m = gm[cur], invd = 1.0f / gden[cur];
    float acc = 0.f;
    for (; i < nend; i += 4) {
        int gi = batch[i];
        if (gi != cur) {
            atomicAdd(&gacc[cur * 128 + c], acc * invd);
            acc = 0.f;
            cur = gi;
            m = gm[cur];
            invd = 1.0f / gden[cur];
        }
        acc = fmaf(expf(gate[i] - m), unpackf(H[(size_t)i * 128 + c]), acc);
    }
    atomicAdd(&gacc[cur * 128 + c], acc * invd);
}

// ---------------- head ----------------
__global__ __launch_bounds__(64) void k_head(const float* __restrict__ gacc, const float* __restrict__ Wh,
                                             const float* __restrict__ bh, float* __restrict__ out) {
    int g = blockIdx.x;
    int l = threadIdx.x;
    float v = gacc[g * 128 + l] * Wh[l] + gacc[g * 128 + 64 + l] * Wh[64 + l];
#pragma unroll
    for (int m = 1; m < 64; m <<= 1) v += __shfl_xor(v, m);
    if (l == 0) out[g] = v + bh[0];
}

extern "C" void kernel_launch(void* const* d_in, const int* in_sizes, int n_in,
                              void* d_out, int out_size, void* d_ws, size_t ws_size,
                              hipStream_t stream) {
    (void)in_sizes; (void)n_in; (void)out_size; (void)ws_size;
    const float* x   = (const float*)d_in[0];
    const int*  ei   = (const int*)d_in[1];
    const int*  batch= (const int*)d_in[2];
    const float* Wl0 = (const float*)d_in[3];
    const float* bl0 = (const float*)d_in[4];
    const float* Wr0 = (const float*)d_in[5];
    const float* Wl1 = (const float*)d_in[6];
    const float* bl1 = (const float*)d_in[7];
    const float* Wr1 = (const float*)d_in[8];
    const float* Wg1 = (const float*)d_in[9];
    const float* bg1 = (const float*)d_in[10];
    const float* Wg2 = (const float*)d_in[11];
    const float* Wh  = (const float*)d_in[13];
    const float* bh  = (const float*)d_in[14];
    float* out = (float*)d_out;

    const int* srcp = ei;
    const int* dstp = ei + NE;

    char* w = (char*)d_ws;
    size_t off = 0;
    auto alloc = [&](size_t bytes) { void* p = w + off; off += (bytes + 255) & ~(size_t)255; return p; };
    u32* AGG   = (u32*)alloc((size_t)NN * 128 * 4);  // packed agg / h2 (in-place)
    u32* H1    = (u32*)alloc((size_t)NN * 128 * 4);  // packed h1
    float* gate  = (float*)alloc((size_t)NN * 4);
    int* cnt     = (int*)alloc((size_t)NN * 4);
    int* rowp    = (int*)alloc((size_t)(NN + 1) * 4);
    int* rowp2   = (int*)alloc((size_t)NN * 4);      // scatter cursor (replaces fill[])
    int* cidx    = (int*)alloc((size_t)NE * 4);
    int* blksum  = (int*)alloc(128 * 4);
    int* blkoff  = (int*)alloc(128 * 4);
    float* gm    = (float*)alloc(NG * 4);
    float* gden  = (float*)alloc(NG * 4);
    float* gacc  = (float*)alloc((size_t)NG * 128 * 4);
    u16* wt      = (u16*)alloc((size_t)5 * 32768 * 2);   // 5 mats x (hi|lo) [c][k] bf16

    hipMemsetAsync(cnt, 0, (size_t)NN * 4, stream);
    hipMemsetAsync(gacc, 0, (size_t)NG * 128 * 4, stream);

    // weight transpose + bf16 hi/lo split (mat order: Wl0, Wr0, Wl1, Wr1, Wg1)
    k_cvtw<<<320, 256, 0, stream>>>(Wl0, Wr0, Wl1, Wr1, Wg1, wt);

    // CSR build (reused by both layers)
    k_hist<<<(NE + 255) / 256, 256, 0, stream>>>(dstp, cnt);
    int nb = (NN + SB - 1) / SB;
    k_scan1<<<nb, SB, 0, stream>>>(cnt, rowp, blksum);
    k_scan2<<<1, 128, 0, stream>>>(blksum, blkoff, nb);
    k_scan3<<<(NN + 1 + 255) / 256, 256, 0, stream>>>(rowp, blkoff, rowp2);
    k_scatter<<<(NE + 255) / 256, 256, 0, stream>>>(srcp, dstp, rowp2, cidx);

    int gs = (NN + 255) / 256;           // 391 GEMM blocks (256-node tiles, 512 thr)
    int ga = (NN * 32 + 255) / 256;      // k_agg: 32 lanes per node
    u16* Wl0hi = wt;
    u16* Wl0lo = wt + 16384;
    u16* Wr0hi = wt + 32768;
    u16* Wr0lo = wt + 49152;
    u16* Wl1hi = wt + 65536;
    u16* Wl1lo = wt + 81920;
    u16* Wr1hi = wt + 98304;
    u16* Wr1lo = wt + 114688;
    u16* Wg1hi = wt + 131072;
    u16* Wg1lo = wt + 147456;
    // layer 0: agg from fp32 x; root A2 = fp32 x
    k_agg<0><<<ga, 256, 0, stream>>>(x, rowp, cidx, AGG);
    k_sage_mf<1><<<gs, 512, 0, stream>>>(AGG, Wl0hi, Wl0lo, bl0, x, Wr0hi, Wr0lo, H1);
    // layer 1: agg from packed h1; root A2 = packed h1; h2 in-place over AGG
    k_agg<1><<<ga, 256, 0, stream>>>(H1, rowp, cidx, AGG);
    k_sage_mf<0><<<gs, 512, 0, stream>>>(AGG, Wl1hi, Wl1lo, bl1, H1, Wr1hi, Wr1lo, AGG);
    // gate + pool + head (H = packed h2 in AGG)
    k_gatef_mf<<<gs, 512, 0, stream>>>(AGG, Wg1hi, Wg1lo, bg1, Wg2, gate);
    k_pstats<<<NG, 512, 0, stream>>>(gate, batch, gm, gden);
    k_pacc<<<(NN + 127) / 128, 512, 0, stream>>>(AGG, gate, batch, gm, gden, gacc);
    k_head<<<NG, 64, 0, stream>>>(gacc, Wh, bh, out);
}

// Round 15
// 532.561 us; speedup vs baseline: 1.1156x; 1.1156x over previous
//
#include <hip/hip_runtime.h>
#include <math.h>

#define NN 100000
#define NE 1600000
#define NG 64
#define NBK 1024      // dst buckets; bucket = d >> 7 -> 782 used
#define BKSHIFT 7

typedef unsigned short u16;
typedef unsigned int u32;
typedef __attribute__((ext_vector_type(8))) short short8;   // 8 bf16 = 4 VGPR
typedef __attribute__((ext_vector_type(4))) float f32x4;    // MFMA C/D

__device__ __forceinline__ float gelu_f(float x) {
    return 0.5f * x * (1.0f + erff(x * 0.7071067811865475f));
}
// round-to-nearest-even fp32 -> bf16
__device__ __forceinline__ u16 f2bf(float f) {
    u32 u = __float_as_uint(f);
    u32 r = u + 0x7FFFu + ((u >> 16) & 1u);
    return (u16)(r >> 16);
}
__device__ __forceinline__ float bf2f(u16 h) { return __uint_as_float(((u32)h) << 16); }
// packed hi/lo bf16 pair in one u32: value ~= hi + lo, rel err ~2^-18
__device__ __forceinline__ u32 packf(float v) {
    u16 h = f2bf(v);
    u16 l = f2bf(v - bf2f(h));
    return (((u32)h) << 16) | (u32)l;
}
__device__ __forceinline__ float unpackf(u32 p) {
    return __uint_as_float(p & 0xFFFF0000u) + __uint_as_float(p << 16);
}
// 8 packed elems (2 uint4) -> hi/lo short8 for MFMA A-operand
__device__ __forceinline__ void unpack8(uint4 q0, uint4 q1, short8& hi, short8& lo) {
    u32 v[8] = {q0.x, q0.y, q0.z, q0.w, q1.x, q1.y, q1.z, q1.w};
#pragma unroll
    for (int e = 0; e < 8; ++e) {
        hi[e] = (short)(v[e] >> 16);
        lo[e] = (short)(v[e] & 0xFFFFu);
    }
}
// 8 fp32 elems (2 float4) -> hi/lo short8
__device__ __forceinline__ void cvt8f(float4 f0, float4 f1, short8& hi, short8& lo) {
    float v[8] = {f0.x, f0.y, f0.z, f0.w, f1.x, f1.y, f1.z, f1.w};
#pragma unroll
    for (int e = 0; e < 8; ++e) {
        u16 h = f2bf(v[e]);
        hi[e] = (short)h;
        lo[e] = (short)f2bf(v[e] - bf2f(h));
    }
}
#define MFMA __builtin_amdgcn_mfma_f32_16x16x32_bf16

// ---------------- CSR build, bucket-sorted ----------------
// Pass A: bucket histogram (LDS-aggregated).
__global__ __launch_bounds__(256) void k_bhist(const int* __restrict__ dstp, int* __restrict__ bcnt) {
    __shared__ int h[NBK];
    for (int i = threadIdx.x; i < NBK; i += 256) h[i] = 0;
    __syncthreads();
    int per = (NE + gridDim.x - 1) / gridDim.x;
    int beg = blockIdx.x * per;
    int end = beg + per; if (end > NE) end = NE;
    for (int e = beg + threadIdx.x; e < end; e += 256)
        atomicAdd(&h[dstp[e] >> BKSHIFT], 1);
    __syncthreads();
    for (int i = threadIdx.x; i < NBK; i += 256)
        if (h[i]) atomicAdd(&bcnt[i], h[i]);
}

// Pass A2: exclusive scan of 1024 bucket counts; boff = offsets, bcur = working copy.
__global__ __launch_bounds__(NBK) void k_bscan(const int* __restrict__ bcnt, int* __restrict__ boff,
                                               int* __restrict__ bcur) {
    __shared__ int s[NBK];
    int tid = threadIdx.x;
    int v = bcnt[tid];
    int run = v;
    s[tid] = v;
    __syncthreads();
    for (int off = 1; off < NBK; off <<= 1) {
        int t = (tid >= off) ? s[tid - off] : 0;
        __syncthreads();
        run += t;
        s[tid] = run;
        __syncthreads();
    }
    boff[tid] = run - v;
    bcur[tid] = run - v;
}

// Pass B: scatter edges into bucket-sorted arrays (srcS, dstS). Per (block,bucket)
// one global reserve atomic; writes land contiguously -> ~1x line utilization.
__global__ __launch_bounds__(256) void k_bscat(const int* __restrict__ srcp, const int* __restrict__ dstp,
                                               int* __restrict__ bcur, int* __restrict__ srcS,
                                               int* __restrict__ dstS) {
    __shared__ int h[NBK];
    __shared__ int basew[NBK];
    for (int i = threadIdx.x; i < NBK; i += 256) h[i] = 0;
    __syncthreads();
    int per = (NE + gridDim.x - 1) / gridDim.x;
    int beg = blockIdx.x * per;
    int end = beg + per; if (end > NE) end = NE;
    for (int e = beg + threadIdx.x; e < end; e += 256)
        atomicAdd(&h[dstp[e] >> BKSHIFT], 1);
    __syncthreads();
    for (int i = threadIdx.x; i < NBK; i += 256) {
        int c = h[i];
        basew[i] = c ? atomicAdd(&bcur[i], c) : 0;
        h[i] = 0;
    }
    __syncthreads();
    for (int e = beg + threadIdx.x; e < end; e += 256) {
        int sv = srcp[e], d = dstp[e];
        int b = d >> BKSHIFT;
        int r = atomicAdd(&h[b], 1);
        int p = basew[b] + r;
        srcS[p] = sv;
        dstS[p] = d;
    }
}

// node histogram on bucket-sorted dstS: atomics hit a ~512B window per chunk (L2-hot)
__global__ void k_hist(const int* __restrict__ dstp, int* __restrict__ cnt) {
    int e = blockIdx.x * 256 + threadIdx.x;
    if (e < NE) atomicAdd(&cnt[dstp[e]], 1);
}

#define SB 1024
__global__ __launch_bounds__(SB) void k_scan1(const int* __restrict__ cnt, int* __restrict__ rowp,
                                              int* __restrict__ blksum) {
    __shared__ int s[SB];
    int tid = threadIdx.x;
    int i = blockIdx.x * SB + tid;
    int v = (i < NN) ? cnt[i] : 0;
    int run = v;
    s[tid] = v;
    __syncthreads();
    for (int off = 1; off < SB; off <<= 1) {
        int t = (tid >= off) ? s[tid - off] : 0;
        __syncthreads();
        run += t;
        s[tid] = run;
        __syncthreads();
    }
    if (i < NN) rowp[i] = run - v;
    if (tid == SB - 1) blksum[blockIdx.x] = run;
}

__global__ void k_scan2(const int* __restrict__ blksum, int* __restrict__ blkoff, int nb) {
    __shared__ int s[128];
    int tid = threadIdx.x;
    int v = (tid < nb) ? blksum[tid] : 0;
    int run = v;
    s[tid] = v;
    __syncthreads();
    for (int off = 1; off < 128; off <<= 1) {
        int t = (tid >= off) ? s[tid - off] : 0;
        __syncthreads();
        run += t;
        s[tid] = run;
        __syncthreads();
    }
    if (tid < nb) blkoff[tid] = run - v;
}

// writes rowp AND the scatter cursor copy rowp2
__global__ void k_scan3(int* __restrict__ rowp, const int* __restrict__ blkoff,
                        int* __restrict__ rowp2) {
    int i = blockIdx.x * 256 + threadIdx.x;
    if (i < NN) {
        int v = rowp[i] + blkoff[i >> 10];
        rowp[i] = v;
        rowp2[i] = v;
    } else if (i == NN) {
        rowp[NN] = NE;
    }
}

// final scatter from bucket-sorted edges: rowp2 atomics + cidx writes land in
// ~8KB hot windows -> lines merge in L2 before writeback (vs 64B/edge before).
__global__ void k_fscat(const int* __restrict__ srcS, const int* __restrict__ dstS,
                        int* __restrict__ rowp2, int* __restrict__ cidx) {
    int e = blockIdx.x * 256 + threadIdx.x;
    if (e < NE) {
        int pos = atomicAdd(&rowp2[dstS[e]], 1);
        cidx[pos] = srcS[e];
    }
}

// ---------------- mean-aggregate: 32 lanes x 16B per node, 8 edges in flight ----------------
// r8-proven config: ~117us, fabric-bound 3.7TB/s (pattern ceiling confirmed r8/r11/r12).
template <int PACKED>
__global__ __launch_bounds__(256) void k_agg(const void* __restrict__ xin, const int* __restrict__ rowp,
                                             const int* __restrict__ cidx, u32* __restrict__ agg) {
    int tid = blockIdx.x * 256 + threadIdx.x;
    int node = tid >> 5;
    int lane = tid & 31;
    if (node >= NN) return;
    int beg = rowp[node], endp = rowp[node + 1];
    const float4* xf = (const float4*)xin;
    const uint4* xp = (const uint4*)xin;
    float sx = 0.f, sy = 0.f, sz = 0.f, sw = 0.f;
    int e = beg;
    for (; e + 7 < endp; e += 8) {
        int idx[8];
#pragma unroll
        for (int u = 0; u < 8; ++u) idx[u] = cidx[e + u];
        if (PACKED) {
            uint4 q[8];
#pragma unroll
            for (int u = 0; u < 8; ++u) q[u] = xp[(size_t)idx[u] * 32 + lane];
#pragma unroll
            for (int u = 0; u < 8; ++u) {
                sx += unpackf(q[u].x); sy += unpackf(q[u].y);
                sz += unpackf(q[u].z); sw += unpackf(q[u].w);
            }
        } else {
            float4 v[8];
#pragma unroll
            for (int u = 0; u < 8; ++u) v[u] = xf[(size_t)idx[u] * 32 + lane];
#pragma unroll
            for (int u = 0; u < 8; ++u) {
                sx += v[u].x; sy += v[u].y; sz += v[u].z; sw += v[u].w;
            }
        }
    }
    for (; e < endp; ++e) {
        int i0 = cidx[e];
        if (PACKED) {
            uint4 q = xp[(size_t)i0 * 32 + lane];
            sx += unpackf(q.x); sy += unpackf(q.y); sz += unpackf(q.z); sw += unpackf(q.w);
        } else {
            float4 v = xf[(size_t)i0 * 32 + lane];
            sx += v.x; sy += v.y; sz += v.z; sw += v.w;
        }
    }
    float inv = 1.0f / fmaxf((float)(endp - beg), 1.0f);
    uint4 o;
    o.x = packf(sx * inv); o.y = packf(sy * inv); o.z = packf(sz * inv); o.w = packf(sw * inv);
    ((uint4*)agg)[(size_t)node * 32 + lane] = o;
}

// ---------------- weight prep: transpose + bf16 hi/lo split (planes) ----------------
__global__ __launch_bounds__(256) void k_cvtw(const float* __restrict__ W0, const float* __restrict__ W1,
                                              const float* __restrict__ W2, const float* __restrict__ W3,
                                              const float* __restrict__ W4, u16* __restrict__ dst) {
    int idx = blockIdx.x * 256 + threadIdx.x;   // 5*16384
    int m = idx >> 14;
    int r = idx & 16383;
    int k = r >> 7, c = r & 127;
    const float* W = (m == 0) ? W0 : (m == 1) ? W1 : (m == 2) ? W2 : (m == 3) ? W3 : W4;
    float v = W[k * 128 + c];
    u16 h = f2bf(v);
    u16 l = f2bf(v - bf2f(h));
    u16* base = dst + (size_t)m * 32768;
    base[c * 128 + k] = h;
    base[16384 + c * 128 + k] = l;
}

// ---------------- fused SAGE layer via bf16x3 MFMA, A-prefetch pipelined ----------------
// 512 thr = 8 waves; wave = 32 nodes (2 M-tiles); block = 256 nodes.
// In-place safety (out may alias A1/A2): wave reads/writes ONLY its own 32 rows;
// prefetch loads are consumed before epilogue stores (wave program order).
template <int A2F32>
__global__ __launch_bounds__(512, 2) void k_sage_mf(const u32* A1, const u16* __restrict__ w1hi,
                                                    const u16* __restrict__ w1lo, const float* __restrict__ b1,
                                                    const void* A2v, const u16* __restrict__ w2hi,
                                                    const u16* __restrict__ w2lo, u32* out) {
    __shared__ u16 lds[4][128][40];
    const int t = threadIdx.x;
    const int lane = t & 63;
    const int w = t >> 6;
    const int l15 = lane & 15;
    const int lg = lane >> 4;
    const int n0 = blockIdx.x * 256 + w * 32;
    f32x4 acc[2][8];
#pragma unroll
    for (int ti = 0; ti < 2; ++ti)
#pragma unroll
        for (int ct = 0; ct < 8; ++ct) acc[ti][ct] = (f32x4){0.f, 0.f, 0.f, 0.f};
    int nA = n0 + l15;
    int nB = n0 + 16 + l15;
    if (nA >= NN) nA = NN - 1;
    if (nB >= NN) nB = NN - 1;
    const u32* a1A = A1 + (size_t)nA * 128;
    const u32* a1B = A1 + (size_t)nB * 128;
    const u32* a2Ap = (const u32*)A2v + (size_t)nA * 128;
    const u32* a2Bp = (const u32*)A2v + (size_t)nB * 128;
    const float* a2Af = (const float*)A2v + (size_t)nA * 128;
    const float* a2Bf = (const float*)A2v + (size_t)nB * 128;
    const int koff = 8 * lg;

    uint4 p1A[2][2], p1B[2][2];
    uint4 p2A[2][2], p2B[2][2];
    float4 f2A[2][2], f2B[2][2];

    {
        const uint4* q;
        q = (const uint4*)(a1A + koff); p1A[0][0] = q[0]; p1A[0][1] = q[1];
        q = (const uint4*)(a1B + koff); p1B[0][0] = q[0]; p1B[0][1] = q[1];
        if (A2F32) {
            const float4* f;
            f = (const float4*)(a2Af + koff); f2A[0][0] = f[0]; f2A[0][1] = f[1];
            f = (const float4*)(a2Bf + koff); f2B[0][0] = f[0]; f2B[0][1] = f[1];
        } else {
            const uint4* q2;
            q2 = (const uint4*)(a2Ap + koff); p2A[0][0] = q2[0]; p2A[0][1] = q2[1];
            q2 = (const uint4*)(a2Bp + koff); p2B[0][0] = q2[0]; p2B[0][1] = q2[1];
        }
    }
#pragma unroll
    for (int kb = 0; kb < 4; ++kb) {
        const int k0 = kb * 32;
        const int cur = kb & 1, nxt = cur ^ 1;
        __syncthreads();
        {   // stage 4 W-slices [128c][32k] bf16: 512 units of 64B, one per thread
            int s = t >> 7, c = t & 127;
            const u16* src = (s == 0) ? w1hi : (s == 1) ? w1lo : (s == 2) ? w2hi : w2lo;
            const uint4* s4 = (const uint4*)(src + (size_t)c * 128 + k0);
            uint4* d4 = (uint4*)&lds[s][c][0];
            d4[0] = s4[0]; d4[1] = s4[1]; d4[2] = s4[2]; d4[3] = s4[3];
        }
        __syncthreads();
        if (kb < 3) {
            const int kn = k0 + 32 + koff;
            const uint4* q;
            q = (const uint4*)(a1A + kn); p1A[nxt][0] = q[0]; p1A[nxt][1] = q[1];
            q = (const uint4*)(a1B + kn); p1B[nxt][0] = q[0]; p1B[nxt][1] = q[1];
            if (A2F32) {
                const float4* f;
                f = (const float4*)(a2Af + kn); f2A[nxt][0] = f[0]; f2A[nxt][1] = f[1];
                f = (const float4*)(a2Bf + kn); f2B[nxt][0] = f[0]; f2B[nxt][1] = f[1];
            } else {
                const uint4* q2;
                q2 = (const uint4*)(a2Ap + kn); p2A[nxt][0] = q2[0]; p2A[nxt][1] = q2[1];
                q2 = (const uint4*)(a2Bp + kn); p2B[nxt][0] = q2[0]; p2B[nxt][1] = q2[1];
            }
        }
        short8 h1A, l1A, h1B, l1B, h2A, l2A, h2B, l2B;
        unpack8(p1A[cur][0], p1A[cur][1], h1A, l1A);
        unpack8(p1B[cur][0], p1B[cur][1], h1B, l1B);
        if (A2F32) {
            cvt8f(f2A[cur][0], f2A[cur][1], h2A, l2A);
            cvt8f(f2B[cur][0], f2B[cur][1], h2B, l2B);
        } else {
            unpack8(p2A[cur][0], p2A[cur][1], h2A, l2A);
            unpack8(p2B[cur][0], p2B[cur][1], h2B, l2B);
        }
#pragma unroll
        for (int ct = 0; ct < 8; ++ct) {
            int c = ct * 16 + l15;
            short8 bh1 = *(const short8*)&lds[0][c][koff];
            short8 bl1 = *(const short8*)&lds[1][c][koff];
            short8 bh2 = *(const short8*)&lds[2][c][koff];
            short8 bl2 = *(const short8*)&lds[3][c][koff];
            acc[0][ct] = MFMA(h1A, bh1, acc[0][ct], 0, 0, 0);
            acc[0][ct] = MFMA(l1A, bh1, acc[0][ct], 0, 0, 0);
            acc[0][ct] = MFMA(h1A, bl1, acc[0][ct], 0, 0, 0);
            acc[0][ct] = MFMA(h2A, bh2, acc[0][ct], 0, 0, 0);
            acc[0][ct] = MFMA(l2A, bh2, acc[0][ct], 0, 0, 0);
            acc[0][ct] = MFMA(h2A, bl2, acc[0][ct], 0, 0, 0);
            acc[1][ct] = MFMA(h1B, bh1, acc[1][ct], 0, 0, 0);
            acc[1][ct] = MFMA(l1B, bh1, acc[1][ct], 0, 0, 0);
            acc[1][ct] = MFMA(h1B, bl1, acc[1][ct], 0, 0, 0);
            acc[1][ct] = MFMA(h2B, bh2, acc[1][ct], 0, 0, 0);
            acc[1][ct] = MFMA(l2B, bh2, acc[1][ct], 0, 0, 0);
            acc[1][ct] = MFMA(h2B, bl2, acc[1][ct], 0, 0, 0);
        }
    }
#pragma unroll
    for (int ti = 0; ti < 2; ++ti) {
#pragma unroll
        for (int ct = 0; ct < 8; ++ct) {
            int c = ct * 16 + l15;
            float bb = b1[c];
#pragma unroll
            for (int r = 0; r < 4; ++r) {
                int node = n0 + ti * 16 + lg * 4 + r;
                if (node < NN) out[(size_t)node * 128 + c] = packf(gelu_f(acc[ti][ct][r] + bb));
            }
        }
    }
}

// ---------------- fused gate via bf16x3 MFMA (packed H input) ----------------
__global__ __launch_bounds__(512, 2) void k_gatef_mf(const u32* __restrict__ H, const u16* __restrict__ wghi,
                                                     const u16* __restrict__ wglo, const float* __restrict__ bg1,
                                                     const float* __restrict__ Wg2, float* __restrict__ gate) {
    __shared__ u16 lds[2][128][40];
    const int t = threadIdx.x;
    const int lane = t & 63;
    const int w = t >> 6;
    const int l15 = lane & 15;
    const int lg = lane >> 4;
    const int n0 = blockIdx.x * 256 + w * 32;
    f32x4 acc[2][8];
#pragma unroll
    for (int ti = 0; ti < 2; ++ti)
#pragma unroll
        for (int ct = 0; ct < 8; ++ct) acc[ti][ct] = (f32x4){0.f, 0.f, 0.f, 0.f};
    int nA = n0 + l15;
    int nB = n0 + 16 + l15;
    if (nA >= NN) nA = NN - 1;
    if (nB >= NN) nB = NN - 1;
    const u32* hA = H + (size_t)nA * 128;
    const u32* hB = H + (size_t)nB * 128;
    const int koff = 8 * lg;
    uint4 pA[2][2], pB[2][2];
    {
        const uint4* q;
        q = (const uint4*)(hA + koff); pA[0][0] = q[0]; pA[0][1] = q[1];
        q = (const uint4*)(hB + koff); pB[0][0] = q[0]; pB[0][1] = q[1];
    }
#pragma unroll
    for (int kb = 0; kb < 4; ++kb) {
        const int k0 = kb * 32;
        const int cur = kb & 1, nxt = cur ^ 1;
        __syncthreads();
        if (t < 256) {  // 2 planes x 128 c
            int s = t >> 7, c = t & 127;
            const u16* src = (s == 0) ? wghi : wglo;
            const uint4* s4 = (const uint4*)(src + (size_t)c * 128 + k0);
            uint4* d4 = (uint4*)&lds[s][c][0];
            d4[0] = s4[0]; d4[1] = s4[1]; d4[2] = s4[2]; d4[3] = s4[3];
        }
        __syncthreads();
        if (kb < 3) {
            const int kn = k0 + 32 + koff;
            const uint4* q;
            q = (const uint4*)(hA + kn); pA[nxt][0] = q[0]; pA[nxt][1] = q[1];
            q = (const uint4*)(hB + kn); pB[nxt][0] = q[0]; pB[nxt][1] = q[1];
        }
        short8 hAh, hAl, hBh, hBl;
        unpack8(pA[cur][0], pA[cur][1], hAh, hAl);
        unpack8(pB[cur][0], pB[cur][1], hBh, hBl);
#pragma unroll
        for (int ct = 0; ct < 8; ++ct) {
            int c = ct * 16 + l15;
            short8 bh = *(const short8*)&lds[0][c][koff];
            short8 bl = *(const short8*)&lds[1][c][koff];
            acc[0][ct] = MFMA(hAh, bh, acc[0][ct], 0, 0, 0);
            acc[0][ct] = MFMA(hAl, bh, acc[0][ct], 0, 0, 0);
            acc[0][ct] = MFMA(hAh, bl, acc[0][ct], 0, 0, 0);
            acc[1][ct] = MFMA(hBh, bh, acc[1][ct], 0, 0, 0);
            acc[1][ct] = MFMA(hBl, bh, acc[1][ct], 0, 0, 0);
            acc[1][ct] = MFMA(hBh, bl, acc[1][ct], 0, 0, 0);
        }
    }
    float p[2][4];
#pragma unroll
    for (int ti = 0; ti < 2; ++ti)
#pragma unroll
        for (int r = 0; r < 4; ++r) p[ti][r] = 0.f;
#pragma unroll
    for (int ct = 0; ct < 8; ++ct) {
        int c = ct * 16 + l15;
        float bb = bg1[c];
        float gv = Wg2[c];
#pragma unroll
        for (int ti = 0; ti < 2; ++ti)
#pragma unroll
            for (int r = 0; r < 4; ++r) p[ti][r] += gelu_f(acc[ti][ct][r] + bb) * gv;
    }
#pragma unroll
    for (int m = 1; m < 16; m <<= 1) {
#pragma unroll
        for (int ti = 0; ti < 2; ++ti)
#pragma unroll
            for (int r = 0; r < 4; ++r) p[ti][r] += __shfl_xor(p[ti][r], m);
    }
    if (l15 == 0) {
#pragma unroll
        for (int ti = 0; ti < 2; ++ti)
#pragma unroll
            for (int r = 0; r < 4; ++r) {
                int node = n0 + ti * 16 + lg * 4 + r;
                if (node < NN) gate[node] = p[ti][r];
            }
    }
}

// ---------------- pooling stage 1 (512 thr) ----------------
__global__ __launch_bounds__(512) void k_pstats(const float* __restrict__ gate, const int* __restrict__ batch,
                                                float* __restrict__ gm, float* __restrict__ gden) {
    int g = blockIdx.x;
    int lo = 0, hi = NN;
    while (lo < hi) { int mid = (lo + hi) >> 1; if (batch[mid] < g) lo = mid + 1; else hi = mid; }
    int start = lo;
    lo = start; hi = NN;
    while (lo < hi) { int mid = (lo + hi) >> 1; if (batch[mid] < g + 1) lo = mid + 1; else hi = mid; }
    int endp = lo;

    __shared__ float red[512];
    int tid = threadIdx.x;

    float m = -1e30f;
    for (int i = start + tid; i < endp; i += 512) m = fmaxf(m, gate[i]);
    red[tid] = m;
    __syncthreads();
    for (int off = 256; off; off >>= 1) {
        if (tid < off) red[tid] = fmaxf(red[tid], red[tid + off]);
        __syncthreads();
    }
    m = red[0];
    __syncthreads();

    float s = 0.f;
    for (int i = start + tid; i < endp; i += 512) s += expf(gate[i] - m);
    red[tid] = s;
    __syncthreads();
    for (int off = 256; off; off >>= 1) {
        if (tid < off) red[tid] += red[tid + off];
        __syncthreads();
    }
    if (tid == 0) { gm[g] = m; gden[g] = red[0]; }
}

// ---------------- pooling stage 2 (packed H; 512 thr, 4 rows in flight) ----------------
__global__ __launch_bounds__(512) void k_pacc(const u32* __restrict__ H, const float* __restrict__ gate,
                                              const int* __restrict__ batch, const float* __restrict__ gm,
                                              const float* __restrict__ gden, float* __restrict__ gacc) {
    int c = threadIdx.x & 127;
    int h = threadIdx.x >> 7;          // 0..3
    int n0 = blockIdx.x * 128;
    int nend = n0 + 128;
    if (nend > NN) nend = NN;
    int i = n0 + h;
    if (i >= nend) return;
    int cur = batch[i];
    float m = gm[cur], invd = 1.0f / gden[cur];
    float acc = 0.f;
    for (; i < nend; i += 4) {
        int gi = batch[i];
        if (gi != cur) {
            atomicAdd(&gacc[cur * 128 + c], acc * invd);
            acc = 0.f;
            cur = gi;
            m = gm[cur];
            invd = 1.0f / gden[cur];
        }
        acc = fmaf(expf(gate[i] - m), unpackf(H[(size_t)i * 128 + c]), acc);
    }
    atomicAdd(&gacc[cur * 128 + c], acc * invd);
}

// ---------------- head ----------------
__global__ __launch_bounds__(64) void k_head(const float* __restrict__ gacc, const float* __restrict__ Wh,
                                             const float* __restrict__ bh, float* __restrict__ out) {
    int g = blockIdx.x;
    int l = threadIdx.x;
    float v = gacc[g * 128 + l] * Wh[l] + gacc[g * 128 + 64 + l] * Wh[64 + l];
#pragma unroll
    for (int m = 1; m < 64; m <<= 1) v += __shfl_xor(v, m);
    if (l == 0) out[g] = v + bh[0];
}

extern "C" void kernel_launch(void* const* d_in, const int* in_sizes, int n_in,
                              void* d_out, int out_size, void* d_ws, size_t ws_size,
                              hipStream_t stream) {
    (void)in_sizes; (void)n_in; (void)out_size; (void)ws_size;
    const float* x   = (const float*)d_in[0];
    const int*  ei   = (const int*)d_in[1];
    const int*  batch= (const int*)d_in[2];
    const float* Wl0 = (const float*)d_in[3];
    const float* bl0 = (const float*)d_in[4];
    const float* Wr0 = (const float*)d_in[5];
    const float* Wl1 = (const float*)d_in[6];
    const float* bl1 = (const float*)d_in[7];
    const float* Wr1 = (const float*)d_in[8];
    const float* Wg1 = (const float*)d_in[9];
    const float* bg1 = (const float*)d_in[10];
    const float* Wg2 = (const float*)d_in[11];
    const float* Wh  = (const float*)d_in[13];
    const float* bh  = (const float*)d_in[14];
    float* out = (float*)d_out;

    const int* srcp = ei;
    const int* dstp = ei + NE;

    char* w = (char*)d_ws;
    size_t off = 0;
    auto alloc = [&](size_t bytes) { void* p = w + off; off += (bytes + 255) & ~(size_t)255; return p; };
    u32* AGG   = (u32*)alloc((size_t)NN * 128 * 4);  // packed agg / h2 (in-place)
    u32* H1    = (u32*)alloc((size_t)NN * 128 * 4);  // packed h1
    float* gate  = (float*)alloc((size_t)NN * 4);
    int* cnt     = (int*)alloc((size_t)NN * 4);
    int* rowp    = (int*)alloc((size_t)(NN + 1) * 4);
    int* rowp2   = (int*)alloc((size_t)NN * 4);      // scatter cursor
    int* cidx    = (int*)alloc((size_t)NE * 4);
    int* srcS    = (int*)alloc((size_t)NE * 4);      // bucket-sorted edges
    int* dstS    = (int*)alloc((size_t)NE * 4);
    int* bcnt    = (int*)alloc(NBK * 4);
    int* boff    = (int*)alloc(NBK * 4);
    int* bcur    = (int*)alloc(NBK * 4);
    int* blksum  = (int*)alloc(128 * 4);
    int* blkoff  = (int*)alloc(128 * 4);
    float* gm    = (float*)alloc(NG * 4);
    float* gden  = (float*)alloc(NG * 4);
    float* gacc  = (float*)alloc((size_t)NG * 128 * 4);
    u16* wt      = (u16*)alloc((size_t)5 * 32768 * 2);   // 5 mats x (hi|lo) [c][k] bf16

    hipMemsetAsync(cnt, 0, (size_t)NN * 4, stream);
    hipMemsetAsync(bcnt, 0, NBK * 4, stream);
    hipMemsetAsync(gacc, 0, (size_t)NG * 128 * 4, stream);

    // weight transpose + bf16 hi/lo split (mat order: Wl0, Wr0, Wl1, Wr1, Wg1)
    k_cvtw<<<320, 256, 0, stream>>>(Wl0, Wr0, Wl1, Wr1, Wg1, wt);

    // CSR build: bucket-sort edges first so all downstream atomics/writes are line-local
    k_bhist<<<256, 256, 0, stream>>>(dstp, bcnt);
    k_bscan<<<1, NBK, 0, stream>>>(bcnt, boff, bcur);
    k_bscat<<<256, 256, 0, stream>>>(srcp, dstp, bcur, srcS, dstS);
    k_hist<<<(NE + 255) / 256, 256, 0, stream>>>(dstS, cnt);
    int nb = (NN + SB - 1) / SB;
    k_scan1<<<nb, SB, 0, stream>>>(cnt, rowp, blksum);
    k_scan2<<<1, 128, 0, stream>>>(blksum, blkoff, nb);
    k_scan3<<<(NN + 1 + 255) / 256, 256, 0, stream>>>(rowp, blkoff, rowp2);
    k_fscat<<<(NE + 255) / 256, 256, 0, stream>>>(srcS, dstS, rowp2, cidx);

    int gs = (NN + 255) / 256;           // 391 GEMM blocks (256-node tiles, 512 thr)
    int ga = (NN * 32 + 255) / 256;      // k_agg: 32 lanes per node
    u16* Wl0hi = wt;
    u16* Wl0lo = wt + 16384;
    u16* Wr0hi = wt + 32768;
    u16* Wr0lo = wt + 49152;
    u16* Wl1hi = wt + 65536;
    u16* Wl1lo = wt + 81920;
    u16* Wr1hi = wt + 98304;
    u16* Wr1lo = wt + 114688;
    u16* Wg1hi = wt + 131072;
    u16* Wg1lo = wt + 147456;
    // layer 0: agg from fp32 x; root A2 = fp32 x
    k_agg<0><<<ga, 256, 0, stream>>>(x, rowp, cidx, AGG);
    k_sage_mf<1><<<gs, 512, 0, stream>>>(AGG, Wl0hi, Wl0lo, bl0, x, Wr0hi, Wr0lo, H1);
    // layer 1: agg from packed h1; root A2 = packed h1; h2 in-place over AGG
    k_agg<1><<<ga, 256, 0, stream>>>(H1, rowp, cidx, AGG);
    k_sage_mf<0><<<gs, 512, 0, stream>>>(AGG, Wl1hi, Wl1lo, bl1, H1, Wr1hi, Wr1lo, AGG);
    // gate + pool + head (H = packed h2 in AGG)
    k_gatef_mf<<<gs, 512, 0, stream>>>(AGG, Wg1hi, Wg1lo, bg1, Wg2, gate);
    k_pstats<<<NG, 512, 0, stream>>>(gate, batch, gm, gden);
    k_pacc<<<(NN + 127) / 128, 512, 0, stream>>>(AGG, gate, batch, gm, gden, gacc);
    k_head<<<NG, 64, 0, stream>>>(gacc, Wh, bh, out);
}

// Round 16
// 451.034 us; speedup vs baseline: 1.3172x; 1.1808x over previous
//
#include <hip/hip_runtime.h>
#include <math.h>

#define NN 100000
#define NE 1600000
#define NG 64
#define NBK 1024      // dst buckets; bucket = d >> 7 -> 782 used
#define BKSHIFT 7

typedef unsigned short u16;
typedef unsigned int u32;
typedef __attribute__((ext_vector_type(8))) short short8;   // 8 bf16 = 4 VGPR
typedef __attribute__((ext_vector_type(4))) float f32x4;    // MFMA C/D

__device__ __forceinline__ float gelu_f(float x) {
    return 0.5f * x * (1.0f + erff(x * 0.7071067811865475f));
}
// round-to-nearest-even fp32 -> bf16
__device__ __forceinline__ u16 f2bf(float f) {
    u32 u = __float_as_uint(f);
    u32 r = u + 0x7FFFu + ((u >> 16) & 1u);
    return (u16)(r >> 16);
}
__device__ __forceinline__ float bf2f(u16 h) { return __uint_as_float(((u32)h) << 16); }
// packed hi/lo bf16 pair in one u32: value ~= hi + lo, rel err ~2^-18
__device__ __forceinline__ u32 packf(float v) {
    u16 h = f2bf(v);
    u16 l = f2bf(v - bf2f(h));
    return (((u32)h) << 16) | (u32)l;
}
__device__ __forceinline__ float unpackf(u32 p) {
    return __uint_as_float(p & 0xFFFF0000u) + __uint_as_float(p << 16);
}
// 8 packed elems (2 uint4) -> hi/lo short8 for MFMA A-operand
__device__ __forceinline__ void unpack8(uint4 q0, uint4 q1, short8& hi, short8& lo) {
    u32 v[8] = {q0.x, q0.y, q0.z, q0.w, q1.x, q1.y, q1.z, q1.w};
#pragma unroll
    for (int e = 0; e < 8; ++e) {
        hi[e] = (short)(v[e] >> 16);
        lo[e] = (short)(v[e] & 0xFFFFu);
    }
}
// 8 fp32 elems (2 float4) -> hi/lo short8
__device__ __forceinline__ void cvt8f(float4 f0, float4 f1, short8& hi, short8& lo) {
    float v[8] = {f0.x, f0.y, f0.z, f0.w, f1.x, f1.y, f1.z, f1.w};
#pragma unroll
    for (int e = 0; e < 8; ++e) {
        u16 h = f2bf(v[e]);
        hi[e] = (short)h;
        lo[e] = (short)f2bf(v[e] - bf2f(h));
    }
}
#define MFMA __builtin_amdgcn_mfma_f32_16x16x32_bf16

// ---------------- CSR build, bucket-sorted ----------------
__global__ __launch_bounds__(256) void k_bhist(const int* __restrict__ dstp, int* __restrict__ bcnt) {
    __shared__ int h[NBK];
    for (int i = threadIdx.x; i < NBK; i += 256) h[i] = 0;
    __syncthreads();
    int per = (NE + gridDim.x - 1) / gridDim.x;
    int beg = blockIdx.x * per;
    int end = beg + per; if (end > NE) end = NE;
    for (int e = beg + threadIdx.x; e < end; e += 256)
        atomicAdd(&h[dstp[e] >> BKSHIFT], 1);
    __syncthreads();
    for (int i = threadIdx.x; i < NBK; i += 256)
        if (h[i]) atomicAdd(&bcnt[i], h[i]);
}

__global__ __launch_bounds__(NBK) void k_bscan(const int* __restrict__ bcnt, int* __restrict__ boff,
                                               int* __restrict__ bcur) {
    __shared__ int s[NBK];
    int tid = threadIdx.x;
    int v = bcnt[tid];
    int run = v;
    s[tid] = v;
    __syncthreads();
    for (int off = 1; off < NBK; off <<= 1) {
        int t = (tid >= off) ? s[tid - off] : 0;
        __syncthreads();
        run += t;
        s[tid] = run;
        __syncthreads();
    }
    boff[tid] = run - v;
    bcur[tid] = run - v;
}

__global__ __launch_bounds__(256) void k_bscat(const int* __restrict__ srcp, const int* __restrict__ dstp,
                                               int* __restrict__ bcur, int* __restrict__ srcS,
                                               int* __restrict__ dstS) {
    __shared__ int h[NBK];
    __shared__ int basew[NBK];
    for (int i = threadIdx.x; i < NBK; i += 256) h[i] = 0;
    __syncthreads();
    int per = (NE + gridDim.x - 1) / gridDim.x;
    int beg = blockIdx.x * per;
    int end = beg + per; if (end > NE) end = NE;
    for (int e = beg + threadIdx.x; e < end; e += 256)
        atomicAdd(&h[dstp[e] >> BKSHIFT], 1);
    __syncthreads();
    for (int i = threadIdx.x; i < NBK; i += 256) {
        int c = h[i];
        basew[i] = c ? atomicAdd(&bcur[i], c) : 0;
        h[i] = 0;
    }
    __syncthreads();
    for (int e = beg + threadIdx.x; e < end; e += 256) {
        int sv = srcp[e], d = dstp[e];
        int b = d >> BKSHIFT;
        int r = atomicAdd(&h[b], 1);
        int p = basew[b] + r;
        srcS[p] = sv;
        dstS[p] = d;
    }
}

__global__ void k_hist(const int* __restrict__ dstp, int* __restrict__ cnt) {
    int e = blockIdx.x * 256 + threadIdx.x;
    if (e < NE) atomicAdd(&cnt[dstp[e]], 1);
}

#define SB 1024
__global__ __launch_bounds__(SB) void k_scan1(const int* __restrict__ cnt, int* __restrict__ rowp,
                                              int* __restrict__ blksum) {
    __shared__ int s[SB];
    int tid = threadIdx.x;
    int i = blockIdx.x * SB + tid;
    int v = (i < NN) ? cnt[i] : 0;
    int run = v;
    s[tid] = v;
    __syncthreads();
    for (int off = 1; off < SB; off <<= 1) {
        int t = (tid >= off) ? s[tid - off] : 0;
        __syncthreads();
        run += t;
        s[tid] = run;
        __syncthreads();
    }
    if (i < NN) rowp[i] = run - v;
    if (tid == SB - 1) blksum[blockIdx.x] = run;
}

__global__ void k_scan2(const int* __restrict__ blksum, int* __restrict__ blkoff, int nb) {
    __shared__ int s[128];
    int tid = threadIdx.x;
    int v = (tid < nb) ? blksum[tid] : 0;
    int run = v;
    s[tid] = v;
    __syncthreads();
    for (int off = 1; off < 128; off <<= 1) {
        int t = (tid >= off) ? s[tid - off] : 0;
        __syncthreads();
        run += t;
        s[tid] = run;
        __syncthreads();
    }
    if (tid < nb) blkoff[tid] = run - v;
}

__global__ void k_scan3(int* __restrict__ rowp, const int* __restrict__ blkoff,
                        int* __restrict__ rowp2) {
    int i = blockIdx.x * 256 + threadIdx.x;
    if (i < NN) {
        int v = rowp[i] + blkoff[i >> 10];
        rowp[i] = v;
        rowp2[i] = v;
    } else if (i == NN) {
        rowp[NN] = NE;
    }
}

__global__ void k_fscat(const int* __restrict__ srcS, const int* __restrict__ dstS,
                        int* __restrict__ rowp2, int* __restrict__ cidx) {
    int e = blockIdx.x * 256 + threadIdx.x;
    if (e < NE) {
        int pos = atomicAdd(&rowp2[dstS[e]], 1);
        cidx[pos] = srcS[e];
    }
}

// ---------------- x -> bf16 mirror (neighbor-gather operand only) ----------------
__global__ __launch_bounds__(256) void k_repack_bf(const float* __restrict__ x, u16* __restrict__ xbf) {
    int i = blockIdx.x * 256 + threadIdx.x;   // 1 float4 -> 1 ushort4 per thread
    if (i >= NN * 32) return;
    float4 v = ((const float4*)x)[i];
    ushort4 o;
    o.x = f2bf(v.x); o.y = f2bf(v.y); o.z = f2bf(v.z); o.w = f2bf(v.w);
    ((ushort4*)xbf)[i] = o;
}

// ---------------- mean-aggregate over bf16 mirror: 32 lanes x 8B, 8 edges in flight ----
// Neighbor rows are bf16 (256B/row): halves gather bytes + per-XCD L2 working set vs
// the 512B packed rows (FETCH 377MB -> ~expected half). Sums in fp32; output packed
// hi/lo u32 mean (GEMM-A-ready). Precision: bf16 rounding only on the neighbor-mean
// path; pooled-logit error ~1e-5 << 1.5e-4 threshold (root/self path stays hi+lo).
__global__ __launch_bounds__(256) void k_agg_bf(const u16* __restrict__ xbf, const int* __restrict__ rowp,
                                                const int* __restrict__ cidx, u32* __restrict__ agg) {
    int tid = blockIdx.x * 256 + threadIdx.x;
    int node = tid >> 5;
    int lane = tid & 31;
    if (node >= NN) return;
    int beg = rowp[node], endp = rowp[node + 1];
    const ushort4* x4 = (const ushort4*)xbf;   // 32 ushort4 per row
    float s0 = 0.f, s1 = 0.f, s2 = 0.f, s3 = 0.f;
    int e = beg;
    for (; e + 7 < endp; e += 8) {
        int idx[8];
#pragma unroll
        for (int u = 0; u < 8; ++u) idx[u] = cidx[e + u];
        ushort4 q[8];
#pragma unroll
        for (int u = 0; u < 8; ++u) q[u] = x4[(size_t)idx[u] * 32 + lane];
#pragma unroll
        for (int u = 0; u < 8; ++u) {
            s0 += bf2f(q[u].x); s1 += bf2f(q[u].y);
            s2 += bf2f(q[u].z); s3 += bf2f(q[u].w);
        }
    }
    for (; e < endp; ++e) {
        ushort4 q = x4[(size_t)cidx[e] * 32 + lane];
        s0 += bf2f(q.x); s1 += bf2f(q.y); s2 += bf2f(q.z); s3 += bf2f(q.w);
    }
    float inv = 1.0f / fmaxf((float)(endp - beg), 1.0f);
    uint4 o;
    o.x = packf(s0 * inv); o.y = packf(s1 * inv); o.z = packf(s2 * inv); o.w = packf(s3 * inv);
    ((uint4*)agg)[(size_t)node * 32 + lane] = o;   // cols 4*lane..4*lane+3
}

// ---------------- weight prep: transpose + bf16 hi/lo split (planes) ----------------
__global__ __launch_bounds__(256) void k_cvtw(const float* __restrict__ W0, const float* __restrict__ W1,
                                              const float* __restrict__ W2, const float* __restrict__ W3,
                                              const float* __restrict__ W4, u16* __restrict__ dst) {
    int idx = blockIdx.x * 256 + threadIdx.x;   // 5*16384
    int m = idx >> 14;
    int r = idx & 16383;
    int k = r >> 7, c = r & 127;
    const float* W = (m == 0) ? W0 : (m == 1) ? W1 : (m == 2) ? W2 : (m == 3) ? W3 : W4;
    float v = W[k * 128 + c];
    u16 h = f2bf(v);
    u16 l = f2bf(v - bf2f(h));
    u16* base = dst + (size_t)m * 32768;
    base[c * 128 + k] = h;
    base[16384 + c * 128 + k] = l;
}

// ---------------- fused SAGE layer via bf16x3 MFMA, A-prefetch pipelined ----------------
// 512 thr = 8 waves; wave = 32 nodes (2 M-tiles); block = 256 nodes.
// WRITEBF=1: also emit a bf16-hi mirror of the output (next layer's gather operand).
// In-place safety (out may alias A1/A2): wave reads/writes ONLY its own 32 rows;
// prefetch loads are consumed before epilogue stores (wave program order).
template <int A2F32, int WRITEBF>
__global__ __launch_bounds__(512, 2) void k_sage_mf(const u32* A1, const u16* __restrict__ w1hi,
                                                    const u16* __restrict__ w1lo, const float* __restrict__ b1,
                                                    const void* A2v, const u16* __restrict__ w2hi,
                                                    const u16* __restrict__ w2lo, u32* out,
                                                    u16* __restrict__ outbf) {
    __shared__ u16 lds[4][128][40];
    const int t = threadIdx.x;
    const int lane = t & 63;
    const int w = t >> 6;
    const int l15 = lane & 15;
    const int lg = lane >> 4;
    const int n0 = blockIdx.x * 256 + w * 32;
    f32x4 acc[2][8];
#pragma unroll
    for (int ti = 0; ti < 2; ++ti)
#pragma unroll
        for (int ct = 0; ct < 8; ++ct) acc[ti][ct] = (f32x4){0.f, 0.f, 0.f, 0.f};
    int nA = n0 + l15;
    int nB = n0 + 16 + l15;
    if (nA >= NN) nA = NN - 1;
    if (nB >= NN) nB = NN - 1;
    const u32* a1A = A1 + (size_t)nA * 128;
    const u32* a1B = A1 + (size_t)nB * 128;
    const u32* a2Ap = (const u32*)A2v + (size_t)nA * 128;
    const u32* a2Bp = (const u32*)A2v + (size_t)nB * 128;
    const float* a2Af = (const float*)A2v + (size_t)nA * 128;
    const float* a2Bf = (const float*)A2v + (size_t)nB * 128;
    const int koff = 8 * lg;

    uint4 p1A[2][2], p1B[2][2];
    uint4 p2A[2][2], p2B[2][2];
    float4 f2A[2][2], f2B[2][2];

    {
        const uint4* q;
        q = (const uint4*)(a1A + koff); p1A[0][0] = q[0]; p1A[0][1] = q[1];
        q = (const uint4*)(a1B + koff); p1B[0][0] = q[0]; p1B[0][1] = q[1];
        if (A2F32) {
            const float4* f;
            f = (const float4*)(a2Af + koff); f2A[0][0] = f[0]; f2A[0][1] = f[1];
            f = (const float4*)(a2Bf + koff); f2B[0][0] = f[0]; f2B[0][1] = f[1];
        } else {
            const uint4* q2;
            q2 = (const uint4*)(a2Ap + koff); p2A[0][0] = q2[0]; p2A[0][1] = q2[1];
            q2 = (const uint4*)(a2Bp + koff); p2B[0][0] = q2[0]; p2B[0][1] = q2[1];
        }
    }
#pragma unroll
    for (int kb = 0; kb < 4; ++kb) {
        const int k0 = kb * 32;
        const int cur = kb & 1, nxt = cur ^ 1;
        __syncthreads();
        {   // stage 4 W-slices [128c][32k] bf16: 512 units of 64B, one per thread
            int s = t >> 7, c = t & 127;
            const u16* src = (s == 0) ? w1hi : (s == 1) ? w1lo : (s == 2) ? w2hi : w2lo;
            const uint4* s4 = (const uint4*)(src + (size_t)c * 128 + k0);
            uint4* d4 = (uint4*)&lds[s][c][0];
            d4[0] = s4[0]; d4[1] = s4[1]; d4[2] = s4[2]; d4[3] = s4[3];
        }
        __syncthreads();
        if (kb < 3) {
            const int kn = k0 + 32 + koff;
            const uint4* q;
            q = (const uint4*)(a1A + kn); p1A[nxt][0] = q[0]; p1A[nxt][1] = q[1];
            q = (const uint4*)(a1B + kn); p1B[nxt][0] = q[0]; p1B[nxt][1] = q[1];
            if (A2F32) {
                const float4* f;
                f = (const float4*)(a2Af + kn); f2A[nxt][0] = f[0]; f2A[nxt][1] = f[1];
                f = (const float4*)(a2Bf + kn); f2B[nxt][0] = f[0]; f2B[nxt][1] = f[1];
            } else {
                const uint4* q2;
                q2 = (const uint4*)(a2Ap + kn); p2A[nxt][0] = q2[0]; p2A[nxt][1] = q2[1];
                q2 = (const uint4*)(a2Bp + kn); p2B[nxt][0] = q2[0]; p2B[nxt][1] = q2[1];
            }
        }
        short8 h1A, l1A, h1B, l1B, h2A, l2A, h2B, l2B;
        unpack8(p1A[cur][0], p1A[cur][1], h1A, l1A);
        unpack8(p1B[cur][0], p1B[cur][1], h1B, l1B);
        if (A2F32) {
            cvt8f(f2A[cur][0], f2A[cur][1], h2A, l2A);
            cvt8f(f2B[cur][0], f2B[cur][1], h2B, l2B);
        } else {
            unpack8(p2A[cur][0], p2A[cur][1], h2A, l2A);
            unpack8(p2B[cur][0], p2B[cur][1], h2B, l2B);
        }
#pragma unroll
        for (int ct = 0; ct < 8; ++ct) {
            int c = ct * 16 + l15;
            short8 bh1 = *(const short8*)&lds[0][c][koff];
            short8 bl1 = *(const short8*)&lds[1][c][koff];
            short8 bh2 = *(const short8*)&lds[2][c][koff];
            short8 bl2 = *(const short8*)&lds[3][c][koff];
            acc[0][ct] = MFMA(h1A, bh1, acc[0][ct], 0, 0, 0);
            acc[0][ct] = MFMA(l1A, bh1, acc[0][ct], 0, 0, 0);
            acc[0][ct] = MFMA(h1A, bl1, acc[0][ct], 0, 0, 0);
            acc[0][ct] = MFMA(h2A, bh2, acc[0][ct], 0, 0, 0);
            acc[0][ct] = MFMA(l2A, bh2, acc[0][ct], 0, 0, 0);
            acc[0][ct] = MFMA(h2A, bl2, acc[0][ct], 0, 0, 0);
            acc[1][ct] = MFMA(h1B, bh1, acc[1][ct], 0, 0, 0);
            acc[1][ct] = MFMA(l1B, bh1, acc[1][ct], 0, 0, 0);
            acc[1][ct] = MFMA(h1B, bl1, acc[1][ct], 0, 0, 0);
            acc[1][ct] = MFMA(h2B, bh2, acc[1][ct], 0, 0, 0);
            acc[1][ct] = MFMA(l2B, bh2, acc[1][ct], 0, 0, 0);
            acc[1][ct] = MFMA(h2B, bl2, acc[1][ct], 0, 0, 0);
        }
    }
#pragma unroll
    for (int ti = 0; ti < 2; ++ti) {
#pragma unroll
        for (int ct = 0; ct < 8; ++ct) {
            int c = ct * 16 + l15;
            float bb = b1[c];
#pragma unroll
            for (int r = 0; r < 4; ++r) {
                int node = n0 + ti * 16 + lg * 4 + r;
                if (node < NN) {
                    float v = gelu_f(acc[ti][ct][r] + bb);
                    u32 p = packf(v);
                    out[(size_t)node * 128 + c] = p;
                    if (WRITEBF) outbf[(size_t)node * 128 + c] = (u16)(p >> 16);
                }
            }
        }
    }
}

// ---------------- fused gate via bf16x3 MFMA (packed H input) ----------------
__global__ __launch_bounds__(512, 2) void k_gatef_mf(const u32* __restrict__ H, const u16* __restrict__ wghi,
                                                     const u16* __restrict__ wglo, const float* __restrict__ bg1,
                                                     const float* __restrict__ Wg2, float* __restrict__ gate) {
    __shared__ u16 lds[2][128][40];
    const int t = threadIdx.x;
    const int lane = t & 63;
    const int w = t >> 6;
    const int l15 = lane & 15;
    const int lg = lane >> 4;
    const int n0 = blockIdx.x * 256 + w * 32;
    f32x4 acc[2][8];
#pragma unroll
    for (int ti = 0; ti < 2; ++ti)
#pragma unroll
        for (int ct = 0; ct < 8; ++ct) acc[ti][ct] = (f32x4){0.f, 0.f, 0.f, 0.f};
    int nA = n0 + l15;
    int nB = n0 + 16 + l15;
    if (nA >= NN) nA = NN - 1;
    if (nB >= NN) nB = NN - 1;
    const u32* hA = H + (size_t)nA * 128;
    const u32* hB = H + (size_t)nB * 128;
    const int koff = 8 * lg;
    uint4 pA[2][2], pB[2][2];
    {
        const uint4* q;
        q = (const uint4*)(hA + koff); pA[0][0] = q[0]; pA[0][1] = q[1];
        q = (const uint4*)(hB + koff); pB[0][0] = q[0]; pB[0][1] = q[1];
    }
#pragma unroll
    for (int kb = 0; kb < 4; ++kb) {
        const int k0 = kb * 32;
        const int cur = kb & 1, nxt = cur ^ 1;
        __syncthreads();
        if (t < 256) {  // 2 planes x 128 c
            int s = t >> 7, c = t & 127;
            const u16* src = (s == 0) ? wghi : wglo;
            const uint4* s4 = (const uint4*)(src + (size_t)c * 128 + k0);
            uint4* d4 = (uint4*)&lds[s][c][0];
            d4[0] = s4[0]; d4[1] = s4[1]; d4[2] = s4[2]; d4[3] = s4[3];
        }
        __syncthreads();
        if (kb < 3) {
            const int kn = k0 + 32 + koff;
            const uint4* q;
            q = (const uint4*)(hA + kn); pA[nxt][0] = q[0]; pA[nxt][1] = q[1];
            q = (const uint4*)(hB + kn); pB[nxt][0] = q[0]; pB[nxt][1] = q[1];
        }
        short8 hAh, hAl, hBh, hBl;
        unpack8(pA[cur][0], pA[cur][1], hAh, hAl);
        unpack8(pB[cur][0], pB[cur][1], hBh, hBl);
#pragma unroll
        for (int ct = 0; ct < 8; ++ct) {
            int c = ct * 16 + l15;
            short8 bh = *(const short8*)&lds[0][c][koff];
            short8 bl = *(const short8*)&lds[1][c][koff];
            acc[0][ct] = MFMA(hAh, bh, acc[0][ct], 0, 0, 0);
            acc[0][ct] = MFMA(hAl, bh, acc[0][ct], 0, 0, 0);
            acc[0][ct] = MFMA(hAh, bl, acc[0][ct], 0, 0, 0);
            acc[1][ct] = MFMA(hBh, bh, acc[1][ct], 0, 0, 0);
            acc[1][ct] = MFMA(hBl, bh, acc[1][ct], 0, 0, 0);
            acc[1][ct] = MFMA(hBh, bl, acc[1][ct], 0, 0, 0);
        }
    }
    float p[2][4];
#pragma unroll
    for (int ti = 0; ti < 2; ++ti)
#pragma unroll
        for (int r = 0; r < 4; ++r) p[ti][r] = 0.f;
#pragma unroll
    for (int ct = 0; ct < 8; ++ct) {
        int c = ct * 16 + l15;
        float bb = bg1[c];
        float gv = Wg2[c];
#pragma unroll
        for (int ti = 0; ti < 2; ++ti)
#pragma unroll
            for (int r = 0; r < 4; ++r) p[ti][r] += gelu_f(acc[ti][ct][r] + bb) * gv;
    }
#pragma unroll
    for (int m = 1; m < 16; m <<= 1) {
#pragma unroll
        for (int ti = 0; ti < 2; ++ti)
#pragma unroll
            for (int r = 0; r < 4; ++r) p[ti][r] += __shfl_xor(p[ti][r], m);
    }
    if (l15 == 0) {
#pragma unroll
        for (int ti = 0; ti < 2; ++ti)
#pragma unroll
            for (int r = 0; r < 4; ++r) {
                int node = n0 + ti * 16 + lg * 4 + r;
                if (node < NN) gate[node] = p[ti][r];
            }
    }
}

// ---------------- pooling stage 1 (512 thr) ----------------
__global__ __launch_bounds__(512) void k_pstats(const float* __restrict__ gate, const int* __restrict__ batch,
                                                float* __restrict__ gm, float* __restrict__ gden) {
    int g = blockIdx.x;
    int lo = 0, hi = NN;
    while (lo < hi) { int mid = (lo + hi) >> 1; if (batch[mid] < g) lo = mid + 1; else hi = mid; }
    int start = lo;
    lo = start; hi = NN;
    while (lo < hi) { int mid = (lo + hi) >> 1; if (batch[mid] < g + 1) lo = mid + 1; else hi = mid; }
    int endp = lo;

    __shared__ float red[512];
    int tid = threadIdx.x;

    float m = -1e30f;
    for (int i = start + tid; i < endp; i += 512) m = fmaxf(m, gate[i]);
    red[tid] = m;
    __syncthreads();
    for (int off = 256; off; off >>= 1) {
        if (tid < off) red[tid] = fmaxf(red[tid], red[tid + off]);
        __syncthreads();
    }
    m = red[0];
    __syncthreads();

    float s = 0.f;
    for (int i = start + tid; i < endp; i += 512) s += expf(gate[i] - m);
    red[tid] = s;
    __syncthreads();
    for (int off = 256; off; off >>= 1) {
        if (tid < off) red[tid] += red[tid + off];
        __syncthreads();
    }
    if (tid == 0) { gm[g] = m; gden[g] = red[0]; }
}

// ---------------- pooling stage 2 (packed H; 512 thr, 4 rows in flight) ----------------
__global__ __launch_bounds__(512) void k_pacc(const u32* __restrict__ H, const float* __restrict__ gate,
                                              const int* __restrict__ batch, const float* __restrict__ gm,
                                              const float* __restrict__ gden, float* __restrict__ gacc) {
    int c = threadIdx.x & 127;
    int h = threadIdx.x >> 7;          // 0..3
    int n0 = blockIdx.x * 128;
    int nend = n0 + 128;
    if (nend > NN) nend = NN;
    int i = n0 + h;
    if (i >= nend) return;
    int cur = batch[i];
    float m = gm[cur], invd = 1.0f / gden[cur];
    float acc = 0.f;
    for (; i < nend; i += 4) {
        int gi = batch[i];
        if (gi != cur) {
            atomicAdd(&gacc[cur * 128 + c], acc * invd);
            acc = 0.f;
            cur = gi;
            m = gm[cur];
            invd = 1.0f / gden[cur];
        }
        acc = fmaf(expf(gate[i] - m), unpackf(H[(size_t)i * 128 + c]), acc);
    }
    atomicAdd(&gacc[cur * 128 + c], acc * invd);
}

// ---------------- head ----------------
__global__ __launch_bounds__(64) void k_head(const float* __restrict__ gacc, const float* __restrict__ Wh,
                                             const float* __restrict__ bh, float* __restrict__ out) {
    int g = blockIdx.x;
    int l = threadIdx.x;
    float v = gacc[g * 128 + l] * Wh[l] + gacc[g * 128 + 64 + l] * Wh[64 + l];
#pragma unroll
    for (int m = 1; m < 64; m <<= 1) v += __shfl_xor(v, m);
    if (l == 0) out[g] = v + bh[0];
}

extern "C" void kernel_launch(void* const* d_in, const int* in_sizes, int n_in,
                              void* d_out, int out_size, void* d_ws, size_t ws_size,
                              hipStream_t stream) {
    (void)in_sizes; (void)n_in; (void)out_size; (void)ws_size;
    const float* x   = (const float*)d_in[0];
    const int*  ei   = (const int*)d_in[1];
    const int*  batch= (const int*)d_in[2];
    const float* Wl0 = (const float*)d_in[3];
    const float* bl0 = (const float*)d_in[4];
    const float* Wr0 = (const float*)d_in[5];
    const float* Wl1 = (const float*)d_in[6];
    const float* bl1 = (const float*)d_in[7];
    const float* Wr1 = (const float*)d_in[8];
    const float* Wg1 = (const float*)d_in[9];
    const float* bg1 = (const float*)d_in[10];
    const float* Wg2 = (const float*)d_in[11];
    const float* Wh  = (const float*)d_in[13];
    const float* bh  = (const float*)d_in[14];
    float* out = (float*)d_out;

    const int* srcp = ei;
    const int* dstp = ei + NE;

    char* w = (char*)d_ws;
    size_t off = 0;
    auto alloc = [&](size_t bytes) { void* p = w + off; off += (bytes + 255) & ~(size_t)255; return p; };
    u32* AGG   = (u32*)alloc((size_t)NN * 128 * 4);  // packed agg / h2 (in-place)
    u32* H1    = (u32*)alloc((size_t)NN * 128 * 4);  // packed h1
    u16* XBF   = (u16*)alloc((size_t)NN * 128 * 2);  // bf16 mirror of x
    u16* H1BF  = (u16*)alloc((size_t)NN * 128 * 2);  // bf16 mirror of h1
    float* gate  = (float*)alloc((size_t)NN * 4);
    int* cnt     = (int*)alloc((size_t)NN * 4);
    int* rowp    = (int*)alloc((size_t)(NN + 1) * 4);
    int* rowp2   = (int*)alloc((size_t)NN * 4);      // scatter cursor
    int* cidx    = (int*)alloc((size_t)NE * 4);
    int* srcS    = (int*)alloc((size_t)NE * 4);      // bucket-sorted edges
    int* dstS    = (int*)alloc((size_t)NE * 4);
    int* bcnt    = (int*)alloc(NBK * 4);
    int* boff    = (int*)alloc(NBK * 4);
    int* bcur    = (int*)alloc(NBK * 4);
    int* blksum  = (int*)alloc(128 * 4);
    int* blkoff  = (int*)alloc(128 * 4);
    float* gm    = (float*)alloc(NG * 4);
    float* gden  = (float*)alloc(NG * 4);
    float* gacc  = (float*)alloc((size_t)NG * 128 * 4);
    u16* wt      = (u16*)alloc((size_t)5 * 32768 * 2);   // 5 mats x (hi|lo) [c][k] bf16

    hipMemsetAsync(cnt, 0, (size_t)NN * 4, stream);
    hipMemsetAsync(bcnt, 0, NBK * 4, stream);
    hipMemsetAsync(gacc, 0, (size_t)NG * 128 * 4, stream);

    // weight transpose + bf16 hi/lo split (mat order: Wl0, Wr0, Wl1, Wr1, Wg1)
    k_cvtw<<<320, 256, 0, stream>>>(Wl0, Wr0, Wl1, Wr1, Wg1, wt);
    // x -> bf16 gather mirror
    k_repack_bf<<<(NN * 32 + 255) / 256, 256, 0, stream>>>(x, XBF);

    // CSR build: bucket-sort edges first so all downstream atomics/writes are line-local
    k_bhist<<<256, 256, 0, stream>>>(dstp, bcnt);
    k_bscan<<<1, NBK, 0, stream>>>(bcnt, boff, bcur);
    k_bscat<<<256, 256, 0, stream>>>(srcp, dstp, bcur, srcS, dstS);
    k_hist<<<(NE + 255) / 256, 256, 0, stream>>>(dstS, cnt);
    int nb = (NN + SB - 1) / SB;
    k_scan1<<<nb, SB, 0, stream>>>(cnt, rowp, blksum);
    k_scan2<<<1, 128, 0, stream>>>(blksum, blkoff, nb);
    k_scan3<<<(NN + 1 + 255) / 256, 256, 0, stream>>>(rowp, blkoff, rowp2);
    k_fscat<<<(NE + 255) / 256, 256, 0, stream>>>(srcS, dstS, rowp2, cidx);

    int gs = (NN + 255) / 256;           // 391 GEMM blocks (256-node tiles, 512 thr)
    int ga = (NN * 32 + 255) / 256;      // agg: 32 lanes per node
    u16* Wl0hi = wt;
    u16* Wl0lo = wt + 16384;
    u16* Wr0hi = wt + 32768;
    u16* Wr0lo = wt + 49152;
    u16* Wl1hi = wt + 65536;
    u16* Wl1lo = wt + 81920;
    u16* Wr1hi = wt + 98304;
    u16* Wr1lo = wt + 114688;
    u16* Wg1hi = wt + 131072;
    u16* Wg1lo = wt + 147456;
    // layer 0: gather bf16 x-mirror; root A2 = fp32 x; write h1 packed + bf16 mirror
    k_agg_bf<<<ga, 256, 0, stream>>>(XBF, rowp, cidx, AGG);
    k_sage_mf<1, 1><<<gs, 512, 0, stream>>>(AGG, Wl0hi, Wl0lo, bl0, x, Wr0hi, Wr0lo, H1, H1BF);
    // layer 1: gather bf16 h1-mirror; root A2 = packed h1; h2 in-place over AGG
    k_agg_bf<<<ga, 256, 0, stream>>>(H1BF, rowp, cidx, AGG);
    k_sage_mf<0, 0><<<gs, 512, 0, stream>>>(AGG, Wl1hi, Wl1lo, bl1, H1, Wr1hi, Wr1lo, AGG, (u16*)nullptr);
    // gate + pool + head (H = packed h2 in AGG)
    k_gatef_mf<<<gs, 512, 0, stream>>>(AGG, Wg1hi, Wg1lo, bg1, Wg2, gate);
    k_pstats<<<NG, 512, 0, stream>>>(gate, batch, gm, gden);
    k_pacc<<<(NN + 127) / 128, 512, 0, stream>>>(AGG, gate, batch, gm, gden, gacc);
    k_head<<<NG, 64, 0, stream>>>(gacc, Wh, bh, out);
}

// Round 17
// 363.638 us; speedup vs baseline: 1.6338x; 1.2403x over previous
//
#include <hip/hip_runtime.h>
#include <math.h>

#define NN 100000
#define NE 1600000
#define NG 64
#define NBK 1024      // dst buckets; bucket = d >> 7 -> 782 used
#define BKSHIFT 7

typedef unsigned short u16;
typedef unsigned int u32;
typedef __attribute__((ext_vector_type(8))) short short8;   // 8 bf16 = 4 VGPR
typedef __attribute__((ext_vector_type(4))) float f32x4;    // MFMA C/D

__device__ __forceinline__ float gelu_f(float x) {
    return 0.5f * x * (1.0f + erff(x * 0.7071067811865475f));
}
// round-to-nearest-even fp32 -> bf16
__device__ __forceinline__ u16 f2bf(float f) {
    u32 u = __float_as_uint(f);
    u32 r = u + 0x7FFFu + ((u >> 16) & 1u);
    return (u16)(r >> 16);
}
__device__ __forceinline__ float bf2f(u16 h) { return __uint_as_float(((u32)h) << 16); }
// packed hi/lo bf16 pair in one u32: value ~= hi + lo, rel err ~2^-18
__device__ __forceinline__ u32 packf(float v) {
    u16 h = f2bf(v);
    u16 l = f2bf(v - bf2f(h));
    return (((u32)h) << 16) | (u32)l;
}
__device__ __forceinline__ float unpackf(u32 p) {
    return __uint_as_float(p & 0xFFFF0000u) + __uint_as_float(p << 16);
}
// 8 packed elems (2 uint4) -> hi/lo short8 for MFMA A-operand
__device__ __forceinline__ void unpack8(uint4 q0, uint4 q1, short8& hi, short8& lo) {
    u32 v[8] = {q0.x, q0.y, q0.z, q0.w, q1.x, q1.y, q1.z, q1.w};
#pragma unroll
    for (int e = 0; e < 8; ++e) {
        hi[e] = (short)(v[e] >> 16);
        lo[e] = (short)(v[e] & 0xFFFFu);
    }
}
// 8 fp32 elems (2 float4) -> hi/lo short8
__device__ __forceinline__ void cvt8f(float4 f0, float4 f1, short8& hi, short8& lo) {
    float v[8] = {f0.x, f0.y, f0.z, f0.w, f1.x, f1.y, f1.z, f1.w};
#pragma unroll
    for (int e = 0; e < 8; ++e) {
        u16 h = f2bf(v[e]);
        hi[e] = (short)h;
        lo[e] = (short)f2bf(v[e] - bf2f(h));
    }
}
#define MFMA __builtin_amdgcn_mfma_f32_16x16x32_bf16

// ---------------- CSR build, bucket-sorted ----------------
// Pass A: bucket histogram (LDS-aggregated), 512 thr.
__global__ __launch_bounds__(512) void k_bhist(const int* __restrict__ dstp, int* __restrict__ bcnt) {
    __shared__ int h[NBK];
    for (int i = threadIdx.x; i < NBK; i += 512) h[i] = 0;
    __syncthreads();
    int per = (NE + gridDim.x - 1) / gridDim.x;
    int beg = blockIdx.x * per;
    int end = beg + per; if (end > NE) end = NE;
    for (int e = beg + threadIdx.x; e < end; e += 512)
        atomicAdd(&h[dstp[e] >> BKSHIFT], 1);
    __syncthreads();
    for (int i = threadIdx.x; i < NBK; i += 512)
        if (h[i]) atomicAdd(&bcnt[i], h[i]);
}

// Pass A2: exclusive scan of 1024 bucket counts; boff = offsets, bcur = working copy.
__global__ __launch_bounds__(NBK) void k_bscan(const int* __restrict__ bcnt, int* __restrict__ boff,
                                               int* __restrict__ bcur) {
    __shared__ int s[NBK];
    int tid = threadIdx.x;
    int v = bcnt[tid];
    int run = v;
    s[tid] = v;
    __syncthreads();
    for (int off = 1; off < NBK; off <<= 1) {
        int t = (tid >= off) ? s[tid - off] : 0;
        __syncthreads();
        run += t;
        s[tid] = run;
        __syncthreads();
    }
    boff[tid] = run - v;
    bcur[tid] = run - v;
}

// Pass B: scatter edges into ONE bucket-sorted uint2 array (src,dst). Per
// (block,bucket) one global reserve atomic; 8-edge chunk = 64B = one full line.
__global__ __launch_bounds__(512) void k_bscat(const int* __restrict__ srcp, const int* __restrict__ dstp,
                                               int* __restrict__ bcur, uint2* __restrict__ esS) {
    __shared__ int h[NBK];
    __shared__ int basew[NBK];
    for (int i = threadIdx.x; i < NBK; i += 512) h[i] = 0;
    __syncthreads();
    int per = (NE + gridDim.x - 1) / gridDim.x;
    int beg = blockIdx.x * per;
    int end = beg + per; if (end > NE) end = NE;
    for (int e = beg + threadIdx.x; e < end; e += 512)
        atomicAdd(&h[dstp[e] >> BKSHIFT], 1);
    __syncthreads();
    for (int i = threadIdx.x; i < NBK; i += 512) {
        int c = h[i];
        basew[i] = c ? atomicAdd(&bcur[i], c) : 0;
        h[i] = 0;
    }
    __syncthreads();
    for (int e = beg + threadIdx.x; e < end; e += 512) {
        int sv = srcp[e], d = dstp[e];
        int b = d >> BKSHIFT;
        int r = atomicAdd(&h[b], 1);
        uint2 ed; ed.x = (u32)sv; ed.y = (u32)d;
        esS[basew[b] + r] = ed;
    }
}

// Pass C: per-bucket CSR finalize — one block per 128-node bucket. LDS node
// histogram + scan -> rowp directly; LDS-cursor scatter -> cidx in the bucket's
// own ~8KB region (hot lines). Replaces hist + 3 scans + fscat.
__global__ __launch_bounds__(256) void k_csr(const uint2* __restrict__ esS, const int* __restrict__ boff,
                                             int* __restrict__ rowp, int* __restrict__ cidx) {
    int b = blockIdx.x;
    int node0 = b << BKSHIFT;
    int t = threadIdx.x;
    __shared__ int cnt0[128];
    __shared__ int s[128];
    __shared__ int cur[128];
    if (t < 128) cnt0[t] = 0;
    __syncthreads();
    int ebeg = boff[b];
    int eend = boff[b + 1];   // buckets >= 782 are empty -> boff[782] == NE
    for (int e = ebeg + t; e < eend; e += 256)
        atomicAdd(&cnt0[(int)esS[e].y - node0], 1);
    __syncthreads();
    int v0 = (t < 128) ? cnt0[t] : 0;
    if (t < 128) s[t] = v0;
    __syncthreads();
    for (int off = 1; off < 128; off <<= 1) {
        int tmp = (t < 128 && t >= off) ? s[t - off] : 0;
        __syncthreads();
        if (t < 128) s[t] += tmp;
        __syncthreads();
    }
    if (t < 128) {
        int excl = s[t] - v0;
        cur[t] = excl;
        int node = node0 + t;
        if (node < NN) rowp[node] = ebeg + excl;
    }
    if (b == gridDim.x - 1 && t == 0) rowp[NN] = NE;
    __syncthreads();
    for (int e = ebeg + t; e < eend; e += 256) {
        uint2 ed = esS[e];
        int ln = (int)ed.y - node0;
        int pos = ebeg + atomicAdd(&cur[ln], 1);
        cidx[pos] = (int)ed.x;
    }
}

// ---------------- x -> bf16 mirror (neighbor-gather operand only) ----------------
__global__ __launch_bounds__(256) void k_repack_bf(const float* __restrict__ x, u16* __restrict__ xbf) {
    int i = blockIdx.x * 256 + threadIdx.x;   // 1 float4 -> 1 ushort4 per thread
    if (i >= NN * 32) return;
    float4 v = ((const float4*)x)[i];
    ushort4 o;
    o.x = f2bf(v.x); o.y = f2bf(v.y); o.z = f2bf(v.z); o.w = f2bf(v.w);
    ((ushort4*)xbf)[i] = o;
}

// ---------------- mean-aggregate over bf16 mirror: 32 lanes x 8B, 8 edges in flight ----
// bf16 neighbor rows (256B): halves gather bytes vs packed 512B (r16: FETCH 377->178MB,
// dur 117->65us). Sums fp32; output packed hi/lo mean. absmax 3.05e-5 (5x margin).
__global__ __launch_bounds__(256) void k_agg_bf(const u16* __restrict__ xbf, const int* __restrict__ rowp,
                                                const int* __restrict__ cidx, u32* __restrict__ agg) {
    int tid = blockIdx.x * 256 + threadIdx.x;
    int node = tid >> 5;
    int lane = tid & 31;
    if (node >= NN) return;
    int beg = rowp[node], endp = rowp[node + 1];
    const ushort4* x4 = (const ushort4*)xbf;   // 32 ushort4 per row
    float s0 = 0.f, s1 = 0.f, s2 = 0.f, s3 = 0.f;
    int e = beg;
    for (; e + 7 < endp; e += 8) {
        int idx[8];
#pragma unroll
        for (int u = 0; u < 8; ++u) idx[u] = cidx[e + u];
        ushort4 q[8];
#pragma unroll
        for (int u = 0; u < 8; ++u) q[u] = x4[(size_t)idx[u] * 32 + lane];
#pragma unroll
        for (int u = 0; u < 8; ++u) {
            s0 += bf2f(q[u].x); s1 += bf2f(q[u].y);
            s2 += bf2f(q[u].z); s3 += bf2f(q[u].w);
        }
    }
    for (; e < endp; ++e) {
        ushort4 q = x4[(size_t)cidx[e] * 32 + lane];
        s0 += bf2f(q.x); s1 += bf2f(q.y); s2 += bf2f(q.z); s3 += bf2f(q.w);
    }
    float inv = 1.0f / fmaxf((float)(endp - beg), 1.0f);
    uint4 o;
    o.x = packf(s0 * inv); o.y = packf(s1 * inv); o.z = packf(s2 * inv); o.w = packf(s3 * inv);
    ((uint4*)agg)[(size_t)node * 32 + lane] = o;   // cols 4*lane..4*lane+3
}

// ---------------- weight prep: transpose + bf16 hi/lo split (planes) ----------------
__global__ __launch_bounds__(256) void k_cvtw(const float* __restrict__ W0, const float* __restrict__ W1,
                                              const float* __restrict__ W2, const float* __restrict__ W3,
                                              const float* __restrict__ W4, u16* __restrict__ dst) {
    int idx = blockIdx.x * 256 + threadIdx.x;   // 5*16384
    int m = idx >> 14;
    int r = idx & 16383;
    int k = r >> 7, c = r & 127;
    const float* W = (m == 0) ? W0 : (m == 1) ? W1 : (m == 2) ? W2 : (m == 3) ? W3 : W4;
    float v = W[k * 128 + c];
    u16 h = f2bf(v);
    u16 l = f2bf(v - bf2f(h));
    u16* base = dst + (size_t)m * 32768;
    base[c * 128 + k] = h;
    base[16384 + c * 128 + k] = l;
}

// ---------------- fused SAGE layer via bf16x3 MFMA, A-prefetch pipelined ----------------
// 512 thr = 8 waves; wave = 32 nodes (2 M-tiles); block = 256 nodes.
// WRITEBF=1: also emit a bf16-hi mirror of the output (next layer's gather operand).
// In-place safety (out may alias A1/A2): wave reads/writes ONLY its own 32 rows;
// prefetch loads are consumed before epilogue stores (wave program order).
template <int A2F32, int WRITEBF>
__global__ __launch_bounds__(512, 2) void k_sage_mf(const u32* A1, const u16* __restrict__ w1hi,
                                                    const u16* __restrict__ w1lo, const float* __restrict__ b1,
                                                    const void* A2v, const u16* __restrict__ w2hi,
                                                    const u16* __restrict__ w2lo, u32* out,
                                                    u16* __restrict__ outbf) {
    __shared__ u16 lds[4][128][40];
    const int t = threadIdx.x;
    const int lane = t & 63;
    const int w = t >> 6;
    const int l15 = lane & 15;
    const int lg = lane >> 4;
    const int n0 = blockIdx.x * 256 + w * 32;
    f32x4 acc[2][8];
#pragma unroll
    for (int ti = 0; ti < 2; ++ti)
#pragma unroll
        for (int ct = 0; ct < 8; ++ct) acc[ti][ct] = (f32x4){0.f, 0.f, 0.f, 0.f};
    int nA = n0 + l15;
    int nB = n0 + 16 + l15;
    if (nA >= NN) nA = NN - 1;
    if (nB >= NN) nB = NN - 1;
    const u32* a1A = A1 + (size_t)nA * 128;
    const u32* a1B = A1 + (size_t)nB * 128;
    const u32* a2Ap = (const u32*)A2v + (size_t)nA * 128;
    const u32* a2Bp = (const u32*)A2v + (size_t)nB * 128;
    const float* a2Af = (const float*)A2v + (size_t)nA * 128;
    const float* a2Bf = (const float*)A2v + (size_t)nB * 128;
    const int koff = 8 * lg;

    uint4 p1A[2][2], p1B[2][2];
    uint4 p2A[2][2], p2B[2][2];
    float4 f2A[2][2], f2B[2][2];

    {
        const uint4* q;
        q = (const uint4*)(a1A + koff); p1A[0][0] = q[0]; p1A[0][1] = q[1];
        q = (const uint4*)(a1B + koff); p1B[0][0] = q[0]; p1B[0][1] = q[1];
        if (A2F32) {
            const float4* f;
            f = (const float4*)(a2Af + koff); f2A[0][0] = f[0]; f2A[0][1] = f[1];
            f = (const float4*)(a2Bf + koff); f2B[0][0] = f[0]; f2B[0][1] = f[1];
        } else {
            const uint4* q2;
            q2 = (const uint4*)(a2Ap + koff); p2A[0][0] = q2[0]; p2A[0][1] = q2[1];
            q2 = (const uint4*)(a2Bp + koff); p2B[0][0] = q2[0]; p2B[0][1] = q2[1];
        }
    }
#pragma unroll
    for (int kb = 0; kb < 4; ++kb) {
        const int k0 = kb * 32;
        const int cur = kb & 1, nxt = cur ^ 1;
        __syncthreads();
        {   // stage 4 W-slices [128c][32k] bf16: 512 units of 64B, one per thread
            int s = t >> 7, c = t & 127;
            const u16* src = (s == 0) ? w1hi : (s == 1) ? w1lo : (s == 2) ? w2hi : w2lo;
            const uint4* s4 = (const uint4*)(src + (size_t)c * 128 + k0);
            uint4* d4 = (uint4*)&lds[s][c][0];
            d4[0] = s4[0]; d4[1] = s4[1]; d4[2] = s4[2]; d4[3] = s4[3];
        }
        __syncthreads();
        if (kb < 3) {
            const int kn = k0 + 32 + koff;
            const uint4* q;
            q = (const uint4*)(a1A + kn); p1A[nxt][0] = q[0]; p1A[nxt][1] = q[1];
            q = (const uint4*)(a1B + kn); p1B[nxt][0] = q[0]; p1B[nxt][1] = q[1];
            if (A2F32) {
                const float4* f;
                f = (const float4*)(a2Af + kn); f2A[nxt][0] = f[0]; f2A[nxt][1] = f[1];
                f = (const float4*)(a2Bf + kn); f2B[nxt][0] = f[0]; f2B[nxt][1] = f[1];
            } else {
                const uint4* q2;
                q2 = (const uint4*)(a2Ap + kn); p2A[nxt][0] = q2[0]; p2A[nxt][1] = q2[1];
                q2 = (const uint4*)(a2Bp + kn); p2B[nxt][0] = q2[0]; p2B[nxt][1] = q2[1];
            }
        }
        short8 h1A, l1A, h1B, l1B, h2A, l2A, h2B, l2B;
        unpack8(p1A[cur][0], p1A[cur][1], h1A, l1A);
        unpack8(p1B[cur][0], p1B[cur][1], h1B, l1B);
        if (A2F32) {
            cvt8f(f2A[cur][0], f2A[cur][1], h2A, l2A);
            cvt8f(f2B[cur][0], f2B[cur][1], h2B, l2B);
        } else {
            unpack8(p2A[cur][0], p2A[cur][1], h2A, l2A);
            unpack8(p2B[cur][0], p2B[cur][1], h2B, l2B);
        }
#pragma unroll
        for (int ct = 0; ct < 8; ++ct) {
            int c = ct * 16 + l15;
            short8 bh1 = *(const short8*)&lds[0][c][koff];
            short8 bl1 = *(const short8*)&lds[1][c][koff];
            short8 bh2 = *(const short8*)&lds[2][c][koff];
            short8 bl2 = *(const short8*)&lds[3][c][koff];
            acc[0][ct] = MFMA(h1A, bh1, acc[0][ct], 0, 0, 0);
            acc[0][ct] = MFMA(l1A, bh1, acc[0][ct], 0, 0, 0);
            acc[0][ct] = MFMA(h1A, bl1, acc[0][ct], 0, 0, 0);
            acc[0][ct] = MFMA(h2A, bh2, acc[0][ct], 0, 0, 0);
            acc[0][ct] = MFMA(l2A, bh2, acc[0][ct], 0, 0, 0);
            acc[0][ct] = MFMA(h2A, bl2, acc[0][ct], 0, 0, 0);
            acc[1][ct] = MFMA(h1B, bh1, acc[1][ct], 0, 0, 0);
            acc[1][ct] = MFMA(l1B, bh1, acc[1][ct], 0, 0, 0);
            acc[1][ct] = MFMA(h1B, bl1, acc[1][ct], 0, 0, 0);
            acc[1][ct] = MFMA(h2B, bh2, acc[1][ct], 0, 0, 0);
            acc[1][ct] = MFMA(l2B, bh2, acc[1][ct], 0, 0, 0);
            acc[1][ct] = MFMA(h2B, bl2, acc[1][ct], 0, 0, 0);
        }
    }
#pragma unroll
    for (int ti = 0; ti < 2; ++ti) {
#pragma unroll
        for (int ct = 0; ct < 8; ++ct) {
            int c = ct * 16 + l15;
            float bb = b1[c];
#pragma unroll
            for (int r = 0; r < 4; ++r) {
                int node = n0 + ti * 16 + lg * 4 + r;
                if (node < NN) {
                    float v = gelu_f(acc[ti][ct][r] + bb);
                    u32 p = packf(v);
                    out[(size_t)node * 128 + c] = p;
                    if (WRITEBF) outbf[(size_t)node * 128 + c] = (u16)(p >> 16);
                }
            }
        }
    }
}

// ---------------- fused gate via bf16x3 MFMA (packed H input) ----------------
__global__ __launch_bounds__(512, 2) void k_gatef_mf(const u32* __restrict__ H, const u16* __restrict__ wghi,
                                                     const u16* __restrict__ wglo, const float* __restrict__ bg1,
                                                     const float* __restrict__ Wg2, float* __restrict__ gate) {
    __shared__ u16 lds[2][128][40];
    const int t = threadIdx.x;
    const int lane = t & 63;
    const int w = t >> 6;
    const int l15 = lane & 15;
    const int lg = lane >> 4;
    const int n0 = blockIdx.x * 256 + w * 32;
    f32x4 acc[2][8];
#pragma unroll
    for (int ti = 0; ti < 2; ++ti)
#pragma unroll
        for (int ct = 0; ct < 8; ++ct) acc[ti][ct] = (f32x4){0.f, 0.f, 0.f, 0.f};
    int nA = n0 + l15;
    int nB = n0 + 16 + l15;
    if (nA >= NN) nA = NN - 1;
    if (nB >= NN) nB = NN - 1;
    const u32* hA = H + (size_t)nA * 128;
    const u32* hB = H + (size_t)nB * 128;
    const int koff = 8 * lg;
    uint4 pA[2][2], pB[2][2];
    {
        const uint4* q;
        q = (const uint4*)(hA + koff); pA[0][0] = q[0]; pA[0][1] = q[1];
        q = (const uint4*)(hB + koff); pB[0][0] = q[0]; pB[0][1] = q[1];
    }
#pragma unroll
    for (int kb = 0; kb < 4; ++kb) {
        const int k0 = kb * 32;
        const int cur = kb & 1, nxt = cur ^ 1;
        __syncthreads();
        if (t < 256) {  // 2 planes x 128 c
            int s = t >> 7, c = t & 127;
            const u16* src = (s == 0) ? wghi : wglo;
            const uint4* s4 = (const uint4*)(src + (size_t)c * 128 + k0);
            uint4* d4 = (uint4*)&lds[s][c][0];
            d4[0] = s4[0]; d4[1] = s4[1]; d4[2] = s4[2]; d4[3] = s4[3];
        }
        __syncthreads();
        if (kb < 3) {
            const int kn = k0 + 32 + koff;
            const uint4* q;
            q = (const uint4*)(hA + kn); pA[nxt][0] = q[0]; pA[nxt][1] = q[1];
            q = (const uint4*)(hB + kn); pB[nxt][0] = q[0]; pB[nxt][1] = q[1];
        }
        short8 hAh, hAl, hBh, hBl;
        unpack8(pA[cur][0], pA[cur][1], hAh, hAl);
        unpack8(pB[cur][0], pB[cur][1], hBh, hBl);
#pragma unroll
        for (int ct = 0; ct < 8; ++ct) {
            int c = ct * 16 + l15;
            short8 bh = *(const short8*)&lds[0][c][koff];
            short8 bl = *(const short8*)&lds[1][c][koff];
            acc[0][ct] = MFMA(hAh, bh, acc[0][ct], 0, 0, 0);
            acc[0][ct] = MFMA(hAl, bh, acc[0][ct], 0, 0, 0);
            acc[0][ct] = MFMA(hAh, bl, acc[0][ct], 0, 0, 0);
            acc[1][ct] = MFMA(hBh, bh, acc[1][ct], 0, 0, 0);
            acc[1][ct] = MFMA(hBl, bh, acc[1][ct], 0, 0, 0);
            acc[1][ct] = MFMA(hBh, bl, acc[1][ct], 0, 0, 0);
        }
    }
    float p[2][4];
#pragma unroll
    for (int ti = 0; ti < 2; ++ti)
#pragma unroll
        for (int r = 0; r < 4; ++r) p[ti][r] = 0.f;
#pragma unroll
    for (int ct = 0; ct < 8; ++ct) {
        int c = ct * 16 + l15;
        float bb = bg1[c];
        float gv = Wg2[c];
#pragma unroll
        for (int ti = 0; ti < 2; ++ti)
#pragma unroll
            for (int r = 0; r < 4; ++r) p[ti][r] += gelu_f(acc[ti][ct][r] + bb) * gv;
    }
#pragma unroll
    for (int m = 1; m < 16; m <<= 1) {
#pragma unroll
        for (int ti = 0; ti < 2; ++ti)
#pragma unroll
            for (int r = 0; r < 4; ++r) p[ti][r] += __shfl_xor(p[ti][r], m);
    }
    if (l15 == 0) {
#pragma unroll
        for (int ti = 0; ti < 2; ++ti)
#pragma unroll
            for (int r = 0; r < 4; ++r) {
                int node = n0 + ti * 16 + lg * 4 + r;
                if (node < NN) gate[node] = p[ti][r];
            }
    }
}

// ---------------- pooling stage 1 (512 thr) ----------------
__global__ __launch_bounds__(512) void k_pstats(const float* __restrict__ gate, const int* __restrict__ batch,
                                                float* __restrict__ gm, float* __restrict__ gden) {
    int g = blockIdx.x;
    int lo = 0, hi = NN;
    while (lo < hi) { int mid = (lo + hi) >> 1; if (batch[mid] < g) lo = mid + 1; else hi = mid; }
    int start = lo;
    lo = start; hi = NN;
    while (lo < hi) { int mid = (lo + hi) >> 1; if (batch[mid] < g + 1) lo = mid + 1; else hi = mid; }
    int endp = lo;

    __shared__ float red[512];
    int tid = threadIdx.x;

    float m = -1e30f;
    for (int i = start + tid; i < endp; i += 512) m = fmaxf(m, gate[i]);
    red[tid] = m;
    __syncthreads();
    for (int off = 256; off; off >>= 1) {
        if (tid < off) red[tid] = fmaxf(red[tid], red[tid + off]);
        __syncthreads();
    }
    m = red[0];
    __syncthreads();

    float s = 0.f;
    for (int i = start + tid; i < endp; i += 512) s += expf(gate[i] - m);
    red[tid] = s;
    __syncthreads();
    for (int off = 256; off; off >>= 1) {
        if (tid < off) red[tid] += red[tid + off];
        __syncthreads();
    }
    if (tid == 0) { gm[g] = m; gden[g] = red[0]; }
}

// ---------------- pooling stage 2 (packed H; 512 thr, 4 rows in flight) ----------------
__global__ __launch_bounds__(512) void k_pacc(const u32* __restrict__ H, const float* __restrict__ gate,
                                              const int* __restrict__ batch, const float* __restrict__ gm,
                                              const float* __restrict__ gden, float* __restrict__ gacc) {
    int c = threadIdx.x & 127;
    int h = threadIdx.x >> 7;          // 0..3
    int n0 = blockIdx.x * 128;
    int nend = n0 + 128;
    if (nend > NN) nend = NN;
    int i = n0 + h;
    if (i >= nend) return;
    int cur = batch[i];
    float m = gm[cur], invd = 1.0f / gden[cur];
    float acc = 0.f;
    for (; i < nend; i += 4) {
        int gi = batch[i];
        if (gi != cur) {
            atomicAdd(&gacc[cur * 128 + c], acc * invd);
            acc = 0.f;
            cur = gi;
            m = gm[cur];
            invd = 1.0f / gden[cur];
        }
        acc = fmaf(expf(gate[i] - m), unpackf(H[(size_t)i * 128 + c]), acc);
    }
    atomicAdd(&gacc[cur * 128 + c], acc * invd);
}

// ---------------- head ----------------
__global__ __launch_bounds__(64) void k_head(const float* __restrict__ gacc, const float* __restrict__ Wh,
                                             const float* __restrict__ bh, float* __restrict__ out) {
    int g = blockIdx.x;
    int l = threadIdx.x;
    float v = gacc[g * 128 + l] * Wh[l] + gacc[g * 128 + 64 + l] * Wh[64 + l];
#pragma unroll
    for (int m = 1; m < 64; m <<= 1) v += __shfl_xor(v, m);
    if (l == 0) out[g] = v + bh[0];
}

extern "C" void kernel_launch(void* const* d_in, const int* in_sizes, int n_in,
                              void* d_out, int out_size, void* d_ws, size_t ws_size,
                              hipStream_t stream) {
    (void)in_sizes; (void)n_in; (void)out_size; (void)ws_size;
    const float* x   = (const float*)d_in[0];
    const int*  ei   = (const int*)d_in[1];
    const int*  batch= (const int*)d_in[2];
    const float* Wl0 = (const float*)d_in[3];
    const float* bl0 = (const float*)d_in[4];
    const float* Wr0 = (const float*)d_in[5];
    const float* Wl1 = (const float*)d_in[6];
    const float* bl1 = (const float*)d_in[7];
    const float* Wr1 = (const float*)d_in[8];
    const float* Wg1 = (const float*)d_in[9];
    const float* bg1 = (const float*)d_in[10];
    const float* Wg2 = (const float*)d_in[11];
    const float* Wh  = (const float*)d_in[13];
    const float* bh  = (const float*)d_in[14];
    float* out = (float*)d_out;

    const int* srcp = ei;
    const int* dstp = ei + NE;

    char* w = (char*)d_ws;
    size_t off = 0;
    auto alloc = [&](size_t bytes) { void* p = w + off; off += (bytes + 255) & ~(size_t)255; return p; };
    u32* AGG   = (u32*)alloc((size_t)NN * 128 * 4);  // packed agg / h2 (in-place)
    u32* H1    = (u32*)alloc((size_t)NN * 128 * 4);  // packed h1
    u16* XBF   = (u16*)alloc((size_t)NN * 128 * 2);  // bf16 mirror of x
    u16* H1BF  = (u16*)alloc((size_t)NN * 128 * 2);  // bf16 mirror of h1
    float* gate  = (float*)alloc((size_t)NN * 4);
    int* rowp    = (int*)alloc((size_t)(NN + 1) * 4);
    int* cidx    = (int*)alloc((size_t)NE * 4);
    uint2* esS   = (uint2*)alloc((size_t)NE * 8);    // bucket-sorted (src,dst) pairs
    int* bcnt    = (int*)alloc(NBK * 4);
    int* boff    = (int*)alloc(NBK * 4);
    int* bcur    = (int*)alloc(NBK * 4);
    float* gm    = (float*)alloc(NG * 4);
    float* gden  = (float*)alloc(NG * 4);
    float* gacc  = (float*)alloc((size_t)NG * 128 * 4);
    u16* wt      = (u16*)alloc((size_t)5 * 32768 * 2);   // 5 mats x (hi|lo) [c][k] bf16

    hipMemsetAsync(bcnt, 0, NBK * 4, stream);
    hipMemsetAsync(gacc, 0, (size_t)NG * 128 * 4, stream);

    // weight transpose + bf16 hi/lo split (mat order: Wl0, Wr0, Wl1, Wr1, Wg1)
    k_cvtw<<<320, 256, 0, stream>>>(Wl0, Wr0, Wl1, Wr1, Wg1, wt);
    // x -> bf16 gather mirror
    k_repack_bf<<<(NN * 32 + 255) / 256, 256, 0, stream>>>(x, XBF);

    // CSR build: bucket-sort -> per-bucket CSR finalize (all writes line-local)
    k_bhist<<<256, 512, 0, stream>>>(dstp, bcnt);
    k_bscan<<<1, NBK, 0, stream>>>(bcnt, boff, bcur);
    k_bscat<<<256, 512, 0, stream>>>(srcp, dstp, bcur, esS);
    k_csr<<<(NN + 127) / 128, 256, 0, stream>>>(esS, boff, rowp, cidx);

    int gs = (NN + 255) / 256;           // 391 GEMM blocks (256-node tiles, 512 thr)
    int ga = (NN * 32 + 255) / 256;      // agg: 32 lanes per node
    u16* Wl0hi = wt;
    u16* Wl0lo = wt + 16384;
    u16* Wr0hi = wt + 32768;
    u16* Wr0lo = wt + 49152;
    u16* Wl1hi = wt + 65536;
    u16* Wl1lo = wt + 81920;
    u16* Wr1hi = wt + 98304;
    u16* Wr1lo = wt + 114688;
    u16* Wg1hi = wt + 131072;
    u16* Wg1lo = wt + 147456;
    // layer 0: gather bf16 x-mirror; root A2 = fp32 x; write h1 packed + bf16 mirror
    k_agg_bf<<<ga, 256, 0, stream>>>(XBF, rowp, cidx, AGG);
    k_sage_mf<1, 1><<<gs, 512, 0, stream>>>(AGG, Wl0hi, Wl0lo, bl0, x, Wr0hi, Wr0lo, H1, H1BF);
    // layer 1: gather bf16 h1-mirror; root A2 = packed h1; h2 in-place over AGG
    k_agg_bf<<<ga, 256, 0, stream>>>(H1BF, rowp, cidx, AGG);
    k_sage_mf<0, 0><<<gs, 512, 0, stream>>>(AGG, Wl1hi, Wl1lo, bl1, H1, Wr1hi, Wr1lo, AGG, (u16*)nullptr);
    // gate + pool + head (H = packed h2 in AGG)
    k_gatef_mf<<<gs, 512, 0, stream>>>(AGG, Wg1hi, Wg1lo, bg1, Wg2, gate);
    k_pstats<<<NG, 512, 0, stream>>>(gate, batch, gm, gden);
    k_pacc<<<(NN + 127) / 128, 512, 0, stream>>>(AGG, gate, batch, gm, gden, gacc);
    k_head<<<NG, 64, 0, stream>>>(gacc, Wh, bh, out);
}